// Round 1
// baseline (492.084 us; speedup 1.0000x reference)
//
#include <hip/hip_runtime.h>

// ---------------------------------------------------------------------------
// GAT GNN: h0 = relu(GAT0(x)); h1 = relu(GAT1(h0));
// out = [x@We+be  ||  h1@Wn+bn]
// Softmax identities used (exact): max-shift invariance (skip segment_max),
// common-denominator factoring (single pass numerator+denominator).
// ---------------------------------------------------------------------------

#define LEAKY_SLOPE 0.2f

// ---------------- GEMM: A[n x 128] @ B[128 x BN] (+bias) (+relu) -----------
template<int BN, bool BIAS, bool RELU>
__global__ __launch_bounds__(256) void gemm_k(const float* __restrict__ A,
                                              const float* __restrict__ B,
                                              const float* __restrict__ bias,
                                              float* __restrict__ C, int n)
{
    constexpr int CG  = BN / 8;      // col groups of 8
    constexpr int RG  = 256 / CG;    // row groups
    constexpr int RPT = 64 / RG;     // rows per thread (4 for BN=128, 2 for BN=64)
    __shared__ float As[64][36];       // pad 4 -> 144B rows, 16B-aligned
    __shared__ float Bs[32][BN + 4];

    const int t  = threadIdx.x;
    const int rb = blockIdx.x * 64;
    const int c0 = (t % CG) * 8;
    const int r0 = (t / CG) * RPT;

    float acc[RPT][8];
#pragma unroll
    for (int i = 0; i < RPT; ++i)
#pragma unroll
        for (int j = 0; j < 8; ++j) acc[i][j] = 0.f;

    for (int kk = 0; kk < 128; kk += 32) {
        // stage A: 64x32 floats
#pragma unroll
        for (int i = 0; i < 2; ++i) {
            int q = t + i * 256;            // 0..511 float4s
            int r = q >> 3;
            int k4 = (q & 7) * 4;
            float4 v = make_float4(0.f, 0.f, 0.f, 0.f);
            int gr = rb + r;
            if (gr < n) v = *(const float4*)&A[(size_t)gr * 128 + kk + k4];
            *(float4*)&As[r][k4] = v;
        }
        // stage B: 32xBN floats
        constexpr int BQ = (32 * BN) / 1024;
#pragma unroll
        for (int i = 0; i < BQ; ++i) {
            int q = t + i * 256;
            int k = q / (BN / 4);
            int c4 = (q % (BN / 4)) * 4;
            *(float4*)&Bs[k][c4] = *(const float4*)&B[(size_t)(kk + k) * BN + c4];
        }
        __syncthreads();

#pragma unroll
        for (int k4 = 0; k4 < 32; k4 += 4) {
            float a[RPT][4];
#pragma unroll
            for (int i = 0; i < RPT; ++i) {
                float4 v = *(const float4*)&As[r0 + i][k4];
                a[i][0] = v.x; a[i][1] = v.y; a[i][2] = v.z; a[i][3] = v.w;
            }
#pragma unroll
            for (int kd = 0; kd < 4; ++kd) {
                float b[8];
                float4 b0v = *(const float4*)&Bs[k4 + kd][c0];
                float4 b1v = *(const float4*)&Bs[k4 + kd][c0 + 4];
                b[0] = b0v.x; b[1] = b0v.y; b[2] = b0v.z; b[3] = b0v.w;
                b[4] = b1v.x; b[5] = b1v.y; b[6] = b1v.z; b[7] = b1v.w;
#pragma unroll
                for (int i = 0; i < RPT; ++i)
#pragma unroll
                    for (int j = 0; j < 8; ++j)
                        acc[i][j] = fmaf(a[i][kd], b[j], acc[i][j]);
            }
        }
        __syncthreads();
    }

#pragma unroll
    for (int i = 0; i < RPT; ++i) {
        int row = rb + r0 + i;
        if (row >= n) continue;
        float o[8];
#pragma unroll
        for (int j = 0; j < 8; ++j) {
            float v = acc[i][j];
            if (BIAS) v += bias[c0 + j];
            if (RELU) v = fmaxf(v, 0.f);
            o[j] = v;
        }
        *(float4*)&C[(size_t)row * BN + c0]     = make_float4(o[0], o[1], o[2], o[3]);
        *(float4*)&C[(size_t)row * BN + c0 + 4] = make_float4(o[4], o[5], o[6], o[7]);
    }
}

// ---------------- attention logits: a_s[n,h], a_d[n,h] ---------------------
// xl row layout = [H*C] flat, att vectors flat [H*C] -> plain per-row dots.
template<int H>
__global__ __launch_bounds__(256) void att_k(const float* __restrict__ xl,
                                             const float* __restrict__ ats,
                                             const float* __restrict__ atd,
                                             float* __restrict__ a_s,
                                             float* __restrict__ a_d, int n)
{
    int node = (blockIdx.x * 256 + threadIdx.x) >> 6;
    int lane = threadIdx.x & 63;
    if (node >= n) return;
    int j = 2 * lane;
    float2 v = *(const float2*)&xl[(size_t)node * 128 + j];
    float ps = v.x * ats[j] + v.y * ats[j + 1];
    float pd = v.x * atd[j] + v.y * atd[j + 1];
    constexpr int GS = 64 / H;   // lanes per head group
#pragma unroll
    for (int off = 1; off < GS; off <<= 1) {
        ps += __shfl_xor(ps, off);
        pd += __shfl_xor(pd, off);
    }
    if ((lane & (GS - 1)) == 0) {
        int h = lane / GS;
        a_s[(size_t)node * H + h] = ps;
        a_d[(size_t)node * H + h] = pd;
    }
}

// ---------------- CSR build ------------------------------------------------
__global__ void zero_k(int* p, int n)
{
    int i = blockIdx.x * 256 + threadIdx.x;
    if (i < n) p[i] = 0;
}

__global__ void count_k(const int* __restrict__ ei, int* __restrict__ deg,
                        int E, int n)
{
    int e = blockIdx.x * 256 + threadIdx.x;
    if (e >= E + n) return;
    int d = (e < E) ? ei[E + e] : (e - E);   // self-loop dst = node id
    atomicAdd(&deg[d], 1);
}

__global__ void scanA_k(const int* __restrict__ deg, int* __restrict__ excl,
                        int* __restrict__ bsum, int n)
{
    __shared__ int sm[256];
    int t = threadIdx.x, i = blockIdx.x * 256 + t;
    int v = (i < n) ? deg[i] : 0;
    sm[t] = v;
    __syncthreads();
    for (int off = 1; off < 256; off <<= 1) {
        int x = (t >= off) ? sm[t - off] : 0;
        __syncthreads();
        sm[t] += x;
        __syncthreads();
    }
    if (i < n) excl[i] = sm[t] - v;
    if (t == 255) bsum[blockIdx.x] = sm[t];
}

__global__ void scanB_k(const int* __restrict__ bsum, int* __restrict__ boff,
                        int nb)
{
    __shared__ int sm[256];
    int t = threadIdx.x;
    int v = (t < nb) ? bsum[t] : 0;
    sm[t] = v;
    __syncthreads();
    for (int off = 1; off < 256; off <<= 1) {
        int x = (t >= off) ? sm[t - off] : 0;
        __syncthreads();
        sm[t] += x;
        __syncthreads();
    }
    if (t < nb) boff[t] = sm[t] - v;
}

__global__ void scanC_k(int* __restrict__ rowptr, const int* __restrict__ boff,
                        int* __restrict__ cursor, int n, int ET)
{
    int i = blockIdx.x * 256 + threadIdx.x;
    if (i < n) {
        int v = rowptr[i] + boff[i >> 8];
        rowptr[i] = v;
        cursor[i] = v;
    }
    if (i == n) rowptr[n] = ET;
}

__global__ void scatter_k(const int* __restrict__ ei, int* __restrict__ cursor,
                          int* __restrict__ col, int E, int n)
{
    int e = blockIdx.x * 256 + threadIdx.x;
    if (e >= E + n) return;
    int s = (e < E) ? ei[e]     : (e - E);
    int d = (e < E) ? ei[E + e] : (e - E);
    int pos = atomicAdd(&cursor[d], 1);
    col[pos] = s;
}

// ---------------- GAT aggregation: one wave per destination node -----------
// out[n][j] = relu( (sum_e ex_e * xl[src_e][j]) / (sum_e ex_e) + bias[j] )
template<int H>
__global__ __launch_bounds__(256) void agg_k(const float* __restrict__ xl,
                                             const float* __restrict__ a_s,
                                             const float* __restrict__ a_d,
                                             const int* __restrict__ rowptr,
                                             const int* __restrict__ col,
                                             const float* __restrict__ bias,
                                             float* __restrict__ out, int n)
{
    int node = (blockIdx.x * 256 + threadIdx.x) >> 6;
    int lane = threadIdx.x & 63;
    if (node >= n) return;
    int h = (H == 1) ? 0 : (lane >> 4);            // 2 channels/lane, C=32 per head
    float ad = a_d[(size_t)node * H + h];
    int p0 = rowptr[node], p1 = rowptr[node + 1];
    float accx = 0.f, accy = 0.f, den = 0.f;
    for (int p = p0; p < p1; ++p) {
        int s = col[p];
        float al = a_s[(size_t)s * H + h] + ad;
        al = (al >= 0.f) ? al : LEAKY_SLOPE * al;
        float w = __expf(al);
        float2 v = *(const float2*)&xl[(size_t)s * 128 + 2 * lane];
        accx = fmaf(w, v.x, accx);
        accy = fmaf(w, v.y, accy);
        den += w;
    }
    float inv = 1.0f / (den + 1e-16f);
    int j = 2 * lane;
    float o0 = fmaxf(fmaf(accx, inv, bias[j]),     0.f);
    float o1 = fmaxf(fmaf(accy, inv, bias[j + 1]), 0.f);
    *(float2*)&out[(size_t)node * 128 + j] = make_float2(o0, o1);
}

// ---------------------------------------------------------------------------
extern "C" void kernel_launch(void* const* d_in, const int* in_sizes, int n_in,
                              void* d_out, int out_size, void* d_ws, size_t ws_size,
                              hipStream_t stream)
{
    const float* x   = (const float*)d_in[0];
    const int*   ei  = (const int*)d_in[1];
    const float* W0  = (const float*)d_in[2];
    const float* as0 = (const float*)d_in[3];
    const float* ad0 = (const float*)d_in[4];
    const float* b0  = (const float*)d_in[5];
    const float* W1  = (const float*)d_in[6];
    const float* as1 = (const float*)d_in[7];
    const float* ad1 = (const float*)d_in[8];
    const float* b1  = (const float*)d_in[9];
    const float* Wn  = (const float*)d_in[10];
    const float* bn  = (const float*)d_in[11];
    const float* We  = (const float*)d_in[12];
    const float* be  = (const float*)d_in[13];

    const int n  = in_sizes[0] / 128;
    const int E  = in_sizes[1] / 2;
    const int ET = E + n;
    float* out = (float*)d_out;

    // workspace carving (256B aligned chunks)
    char* w = (char*)d_ws;
    auto carve = [&](size_t bytes) -> void* {
        void* p = (void*)w;
        w += (bytes + 255) & ~(size_t)255;
        return p;
    };
    float* xl    = (float*)carve((size_t)n * 128 * 4);   // projected features (both layers)
    float* hbuf  = (float*)carve((size_t)n * 128 * 4);   // h0 then h1 (aliased)
    float* a_s   = (float*)carve((size_t)n * 4 * 4);
    float* a_d   = (float*)carve((size_t)n * 4 * 4);
    int*   deg   = (int*)carve((size_t)n * 4);
    int*   rowp  = (int*)carve((size_t)(n + 1) * 4);
    int*   curs  = (int*)carve((size_t)n * 4);
    int*   colv  = (int*)carve((size_t)ET * 4);
    int*   bsum  = (int*)carve(1024);
    int*   boff  = (int*)carve(1024);

    const int gN64 = (n + 63) / 64;
    const int gWv  = (n + 3) / 4;       // one wave per node, 4 waves/block
    const int gE   = (ET + 255) / 256;
    const int NB   = (n + 255) / 256;

    // ---- CSR by destination (shared by both layers) ----
    zero_k   <<<NB, 256, 0, stream>>>(deg, n);
    count_k  <<<gE, 256, 0, stream>>>(ei, deg, E, n);
    scanA_k  <<<NB, 256, 0, stream>>>(deg, rowp, bsum, n);
    scanB_k  <<<1, 256, 0, stream>>>(bsum, boff, NB);
    scanC_k  <<<(n + 256) / 256, 256, 0, stream>>>(rowp, boff, curs, n, ET);
    scatter_k<<<gE, 256, 0, stream>>>(ei, curs, colv, E, n);

    // ---- layer 0: H=4, C=32 ----
    gemm_k<128, false, false><<<gN64, 256, 0, stream>>>(x, W0, nullptr, xl, n);
    att_k<4><<<gWv, 256, 0, stream>>>(xl, as0, ad0, a_s, a_d, n);
    agg_k<4><<<gWv, 256, 0, stream>>>(xl, a_s, a_d, rowp, colv, b0, hbuf, n);

    // ---- layer 1: H=1, C=128 ----
    gemm_k<128, false, false><<<gN64, 256, 0, stream>>>(hbuf, W1, nullptr, xl, n);
    att_k<1><<<gWv, 256, 0, stream>>>(xl, as1, ad1, a_s, a_d, n);
    agg_k<1><<<gWv, 256, 0, stream>>>(xl, a_s, a_d, rowp, colv, b1, hbuf, n);

    // ---- projection heads: out = [h_ego || h_neighbor] ----
    gemm_k<64, true, false><<<gN64, 256, 0, stream>>>(x,    We, be, out, n);
    gemm_k<64, true, false><<<gN64, 256, 0, stream>>>(hbuf, Wn, bn, out + (size_t)n * 64, n);
}

// Round 2
// 420.616 us; speedup vs baseline: 1.1699x; 1.1699x over previous
//
#include <hip/hip_runtime.h>

// ---------------------------------------------------------------------------
// GAT GNN: h0 = relu(GAT0(x)); h1 = relu(GAT1(h0));
// out = [x@We+be  ||  h1@Wn+bn]
// Softmax identities used (exact): max-shift invariance (skip segment_max),
// common-denominator factoring (single pass numerator+denominator).
// R2: agg_k latency-bound fix — shfl-batched col indices + 8-deep load
//     pipeline (was: serial col->a_s->xl chain per edge, VALUBusy 25%).
// ---------------------------------------------------------------------------

#define LEAKY_SLOPE 0.2f

// ---------------- GEMM: A[n x 128] @ B[128 x BN] (+bias) (+relu) -----------
template<int BN, bool BIAS, bool RELU>
__global__ __launch_bounds__(256) void gemm_k(const float* __restrict__ A,
                                              const float* __restrict__ B,
                                              const float* __restrict__ bias,
                                              float* __restrict__ C, int n)
{
    constexpr int CG  = BN / 8;      // col groups of 8
    constexpr int RG  = 256 / CG;    // row groups
    constexpr int RPT = 64 / RG;     // rows per thread (4 for BN=128, 2 for BN=64)
    __shared__ float As[64][36];       // pad 4 -> 144B rows, 16B-aligned
    __shared__ float Bs[32][BN + 4];

    const int t  = threadIdx.x;
    const int rb = blockIdx.x * 64;
    const int c0 = (t % CG) * 8;
    const int r0 = (t / CG) * RPT;

    float acc[RPT][8];
#pragma unroll
    for (int i = 0; i < RPT; ++i)
#pragma unroll
        for (int j = 0; j < 8; ++j) acc[i][j] = 0.f;

    for (int kk = 0; kk < 128; kk += 32) {
        // stage A: 64x32 floats
#pragma unroll
        for (int i = 0; i < 2; ++i) {
            int q = t + i * 256;            // 0..511 float4s
            int r = q >> 3;
            int k4 = (q & 7) * 4;
            float4 v = make_float4(0.f, 0.f, 0.f, 0.f);
            int gr = rb + r;
            if (gr < n) v = *(const float4*)&A[(size_t)gr * 128 + kk + k4];
            *(float4*)&As[r][k4] = v;
        }
        // stage B: 32xBN floats
        constexpr int BQ = (32 * BN) / 1024;
#pragma unroll
        for (int i = 0; i < BQ; ++i) {
            int q = t + i * 256;
            int k = q / (BN / 4);
            int c4 = (q % (BN / 4)) * 4;
            *(float4*)&Bs[k][c4] = *(const float4*)&B[(size_t)(kk + k) * BN + c4];
        }
        __syncthreads();

#pragma unroll
        for (int k4 = 0; k4 < 32; k4 += 4) {
            float a[RPT][4];
#pragma unroll
            for (int i = 0; i < RPT; ++i) {
                float4 v = *(const float4*)&As[r0 + i][k4];
                a[i][0] = v.x; a[i][1] = v.y; a[i][2] = v.z; a[i][3] = v.w;
            }
#pragma unroll
            for (int kd = 0; kd < 4; ++kd) {
                float b[8];
                float4 b0v = *(const float4*)&Bs[k4 + kd][c0];
                float4 b1v = *(const float4*)&Bs[k4 + kd][c0 + 4];
                b[0] = b0v.x; b[1] = b0v.y; b[2] = b0v.z; b[3] = b0v.w;
                b[4] = b1v.x; b[5] = b1v.y; b[6] = b1v.z; b[7] = b1v.w;
#pragma unroll
                for (int i = 0; i < RPT; ++i)
#pragma unroll
                    for (int j = 0; j < 8; ++j)
                        acc[i][j] = fmaf(a[i][kd], b[j], acc[i][j]);
            }
        }
        __syncthreads();
    }

#pragma unroll
    for (int i = 0; i < RPT; ++i) {
        int row = rb + r0 + i;
        if (row >= n) continue;
        float o[8];
#pragma unroll
        for (int j = 0; j < 8; ++j) {
            float v = acc[i][j];
            if (BIAS) v += bias[c0 + j];
            if (RELU) v = fmaxf(v, 0.f);
            o[j] = v;
        }
        *(float4*)&C[(size_t)row * BN + c0]     = make_float4(o[0], o[1], o[2], o[3]);
        *(float4*)&C[(size_t)row * BN + c0 + 4] = make_float4(o[4], o[5], o[6], o[7]);
    }
}

// ---------------- attention logits: a_s[n,h], a_d[n,h] ---------------------
template<int H>
__global__ __launch_bounds__(256) void att_k(const float* __restrict__ xl,
                                             const float* __restrict__ ats,
                                             const float* __restrict__ atd,
                                             float* __restrict__ a_s,
                                             float* __restrict__ a_d, int n)
{
    int node = (blockIdx.x * 256 + threadIdx.x) >> 6;
    int lane = threadIdx.x & 63;
    if (node >= n) return;
    int j = 2 * lane;
    float2 v = *(const float2*)&xl[(size_t)node * 128 + j];
    float ps = v.x * ats[j] + v.y * ats[j + 1];
    float pd = v.x * atd[j] + v.y * atd[j + 1];
    constexpr int GS = 64 / H;   // lanes per head group
#pragma unroll
    for (int off = 1; off < GS; off <<= 1) {
        ps += __shfl_xor(ps, off);
        pd += __shfl_xor(pd, off);
    }
    if ((lane & (GS - 1)) == 0) {
        int h = lane / GS;
        a_s[(size_t)node * H + h] = ps;
        a_d[(size_t)node * H + h] = pd;
    }
}

// ---------------- CSR build ------------------------------------------------
__global__ void zero_k(int* p, int n)
{
    int i = blockIdx.x * 256 + threadIdx.x;
    if (i < n) p[i] = 0;
}

__global__ void count_k(const int* __restrict__ ei, int* __restrict__ deg,
                        int E, int n)
{
    int e = blockIdx.x * 256 + threadIdx.x;
    if (e >= E + n) return;
    int d = (e < E) ? ei[E + e] : (e - E);   // self-loop dst = node id
    atomicAdd(&deg[d], 1);
}

__global__ void scanA_k(const int* __restrict__ deg, int* __restrict__ excl,
                        int* __restrict__ bsum, int n)
{
    __shared__ int sm[256];
    int t = threadIdx.x, i = blockIdx.x * 256 + t;
    int v = (i < n) ? deg[i] : 0;
    sm[t] = v;
    __syncthreads();
    for (int off = 1; off < 256; off <<= 1) {
        int x = (t >= off) ? sm[t - off] : 0;
        __syncthreads();
        sm[t] += x;
        __syncthreads();
    }
    if (i < n) excl[i] = sm[t] - v;
    if (t == 255) bsum[blockIdx.x] = sm[t];
}

__global__ void scanB_k(const int* __restrict__ bsum, int* __restrict__ boff,
                        int nb)
{
    __shared__ int sm[256];
    int t = threadIdx.x;
    int v = (t < nb) ? bsum[t] : 0;
    sm[t] = v;
    __syncthreads();
    for (int off = 1; off < 256; off <<= 1) {
        int x = (t >= off) ? sm[t - off] : 0;
        __syncthreads();
        sm[t] += x;
        __syncthreads();
    }
    if (t < nb) boff[t] = sm[t] - v;
}

__global__ void scanC_k(int* __restrict__ rowptr, const int* __restrict__ boff,
                        int* __restrict__ cursor, int n, int ET)
{
    int i = blockIdx.x * 256 + threadIdx.x;
    if (i < n) {
        int v = rowptr[i] + boff[i >> 8];
        rowptr[i] = v;
        cursor[i] = v;
    }
    if (i == n) rowptr[n] = ET;
}

__global__ void scatter_k(const int* __restrict__ ei, int* __restrict__ cursor,
                          int* __restrict__ col, int E, int n)
{
    int e = blockIdx.x * 256 + threadIdx.x;
    if (e >= E + n) return;
    int s = (e < E) ? ei[e]     : (e - E);
    int d = (e < E) ? ei[E + e] : (e - E);
    int pos = atomicAdd(&cursor[d], 1);
    col[pos] = s;
}

// ---------------- GAT aggregation: one wave per destination node -----------
// R2: latency-hiding restructure.
//  - col indices fetched once per 64-edge chunk via a coalesced per-lane load,
//    then broadcast with __shfl (ds_bpermute, ~50cyc, off the VMEM path).
//  - 8-deep software pipeline: 8 independent a_s broadcast-loads + 8
//    coalesced 512B xl gathers in flight before the FMAs consume them.
template<int H>
__global__ __launch_bounds__(256) void agg_k(const float* __restrict__ xl,
                                             const float* __restrict__ a_s,
                                             const float* __restrict__ a_d,
                                             const int* __restrict__ rowptr,
                                             const int* __restrict__ col,
                                             const float* __restrict__ bias,
                                             float* __restrict__ out, int n)
{
    int node = (blockIdx.x * 256 + threadIdx.x) >> 6;
    int lane = threadIdx.x & 63;
    if (node >= n) return;
    int h = (H == 1) ? 0 : (lane >> 4);            // 2 channels/lane, C=32 per head
    float ad = a_d[(size_t)node * H + h];
    int p0 = rowptr[node], p1 = rowptr[node + 1];
    float accx = 0.f, accy = 0.f, den = 0.f;
    const float* xlj = xl + 2 * lane;

    for (int base = p0; base < p1; base += 64) {
        int m = p1 - base;
        if (m > 64) m = 64;
        // one coalesced load of up to 64 indices (clamped lanes re-read last)
        int cv = col[base + (lane < m ? lane : m - 1)];
        int j = 0;
        for (; j + 8 <= m; j += 8) {
            int s[8];
#pragma unroll
            for (int q = 0; q < 8; ++q) s[q] = __shfl(cv, j + q);
            float as[8];
            float2 v[8];
#pragma unroll
            for (int q = 0; q < 8; ++q) as[q] = a_s[(size_t)s[q] * H + h];
#pragma unroll
            for (int q = 0; q < 8; ++q) v[q] = *(const float2*)&xlj[(size_t)s[q] * 128];
#pragma unroll
            for (int q = 0; q < 8; ++q) {
                float al = as[q] + ad;
                al = (al >= 0.f) ? al : LEAKY_SLOPE * al;
                float w = __expf(al);
                accx = fmaf(w, v[q].x, accx);
                accy = fmaf(w, v[q].y, accy);
                den += w;
            }
        }
        // tail (< 8 edges)
        int rem = m - j;
        if (rem > 0) {
            int s[8];
            float as[8];
            float2 v[8];
#pragma unroll
            for (int q = 0; q < 8; ++q) {
                int jj = (q < rem) ? (j + q) : j;       // dup edge j, weight 0 later
                s[q] = __shfl(cv, jj);
            }
#pragma unroll
            for (int q = 0; q < 8; ++q) as[q] = a_s[(size_t)s[q] * H + h];
#pragma unroll
            for (int q = 0; q < 8; ++q) v[q] = *(const float2*)&xlj[(size_t)s[q] * 128];
#pragma unroll
            for (int q = 0; q < 8; ++q) {
                float al = as[q] + ad;
                al = (al >= 0.f) ? al : LEAKY_SLOPE * al;
                float w = (q < rem) ? __expf(al) : 0.f;
                accx = fmaf(w, v[q].x, accx);
                accy = fmaf(w, v[q].y, accy);
                den += w;
            }
        }
    }

    float inv = 1.0f / (den + 1e-16f);
    int j = 2 * lane;
    float o0 = fmaxf(fmaf(accx, inv, bias[j]),     0.f);
    float o1 = fmaxf(fmaf(accy, inv, bias[j + 1]), 0.f);
    *(float2*)&out[(size_t)node * 128 + j] = make_float2(o0, o1);
}

// ---------------------------------------------------------------------------
extern "C" void kernel_launch(void* const* d_in, const int* in_sizes, int n_in,
                              void* d_out, int out_size, void* d_ws, size_t ws_size,
                              hipStream_t stream)
{
    const float* x   = (const float*)d_in[0];
    const int*   ei  = (const int*)d_in[1];
    const float* W0  = (const float*)d_in[2];
    const float* as0 = (const float*)d_in[3];
    const float* ad0 = (const float*)d_in[4];
    const float* b0  = (const float*)d_in[5];
    const float* W1  = (const float*)d_in[6];
    const float* as1 = (const float*)d_in[7];
    const float* ad1 = (const float*)d_in[8];
    const float* b1  = (const float*)d_in[9];
    const float* Wn  = (const float*)d_in[10];
    const float* bn  = (const float*)d_in[11];
    const float* We  = (const float*)d_in[12];
    const float* be  = (const float*)d_in[13];

    const int n  = in_sizes[0] / 128;
    const int E  = in_sizes[1] / 2;
    const int ET = E + n;
    float* out = (float*)d_out;

    // workspace carving (256B aligned chunks)
    char* w = (char*)d_ws;
    auto carve = [&](size_t bytes) -> void* {
        void* p = (void*)w;
        w += (bytes + 255) & ~(size_t)255;
        return p;
    };
    float* xl    = (float*)carve((size_t)n * 128 * 4);   // projected features (both layers)
    float* hbuf  = (float*)carve((size_t)n * 128 * 4);   // h0 then h1 (aliased)
    float* a_s   = (float*)carve((size_t)n * 4 * 4);
    float* a_d   = (float*)carve((size_t)n * 4 * 4);
    int*   deg   = (int*)carve((size_t)n * 4);
    int*   rowp  = (int*)carve((size_t)(n + 1) * 4);
    int*   curs  = (int*)carve((size_t)n * 4);
    int*   colv  = (int*)carve((size_t)ET * 4);
    int*   bsum  = (int*)carve(1024);
    int*   boff  = (int*)carve(1024);

    const int gN64 = (n + 63) / 64;
    const int gWv  = (n + 3) / 4;       // one wave per node, 4 waves/block
    const int gE   = (ET + 255) / 256;
    const int NB   = (n + 255) / 256;

    // ---- CSR by destination (shared by both layers) ----
    zero_k   <<<NB, 256, 0, stream>>>(deg, n);
    count_k  <<<gE, 256, 0, stream>>>(ei, deg, E, n);
    scanA_k  <<<NB, 256, 0, stream>>>(deg, rowp, bsum, n);
    scanB_k  <<<1, 256, 0, stream>>>(bsum, boff, NB);
    scanC_k  <<<(n + 256) / 256, 256, 0, stream>>>(rowp, boff, curs, n, ET);
    scatter_k<<<gE, 256, 0, stream>>>(ei, curs, colv, E, n);

    // ---- layer 0: H=4, C=32 ----
    gemm_k<128, false, false><<<gN64, 256, 0, stream>>>(x, W0, nullptr, xl, n);
    att_k<4><<<gWv, 256, 0, stream>>>(xl, as0, ad0, a_s, a_d, n);
    agg_k<4><<<gWv, 256, 0, stream>>>(xl, a_s, a_d, rowp, colv, b0, hbuf, n);

    // ---- layer 1: H=1, C=128 ----
    gemm_k<128, false, false><<<gN64, 256, 0, stream>>>(hbuf, W1, nullptr, xl, n);
    att_k<1><<<gWv, 256, 0, stream>>>(xl, as1, ad1, a_s, a_d, n);
    agg_k<1><<<gWv, 256, 0, stream>>>(xl, a_s, a_d, rowp, colv, b1, hbuf, n);

    // ---- projection heads: out = [h_ego || h_neighbor] ----
    gemm_k<64, true, false><<<gN64, 256, 0, stream>>>(x,    We, be, out, n);
    gemm_k<64, true, false><<<gN64, 256, 0, stream>>>(hbuf, Wn, bn, out + (size_t)n * 64, n);
}

// Round 3
// 323.701 us; speedup vs baseline: 1.5202x; 1.2994x over previous
//
#include <hip/hip_runtime.h>

// ---------------------------------------------------------------------------
// GAT GNN: h0 = relu(GAT0(x)); h1 = relu(GAT1(h0));
// out = [x@We+be  ||  h1@Wn+bn]
// R3: all node features bf16 (halves the dominant edge-gather traffic);
//     GEMMs via v_mfma_f32_16x16x32_bf16 with fp32 accumulate.
// Softmax identities (exact): max-shift invariance, common-denominator.
// ---------------------------------------------------------------------------

#define LEAKY_SLOPE 0.2f

typedef __attribute__((ext_vector_type(8))) short s16x8;
typedef __attribute__((ext_vector_type(4))) float f32x4;

static __device__ __forceinline__ unsigned short f2bf(float f)
{
    unsigned x = __float_as_uint(f);
    unsigned r = (x + 0x7fffu + ((x >> 16) & 1u)) >> 16;   // RNE
    return (unsigned short)r;
}
static __device__ __forceinline__ float bfhi(unsigned u) { return __uint_as_float(u & 0xffff0000u); }
static __device__ __forceinline__ float bflo(unsigned u) { return __uint_as_float(u << 16); }

// ---------------- fp32 -> bf16 cast (x) ------------------------------------
__global__ __launch_bounds__(256) void cast4_k(const float* __restrict__ src,
                                               unsigned short* __restrict__ dst, int n4)
{
    int i = blockIdx.x * 256 + threadIdx.x;
    if (i >= n4) return;
    float4 v = ((const float4*)src)[i];
    ushort4 o;
    o.x = f2bf(v.x); o.y = f2bf(v.y); o.z = f2bf(v.z); o.w = f2bf(v.w);
    ((ushort4*)dst)[i] = o;
}

// ---------------- weight pack: fp32 [128 x BN] -> bf16 octet layout --------
// P[((k/8)*BN + n)*8 + (k%8)] = bf16(W[k][n])   (one fused kernel, 4 mats)
__global__ __launch_bounds__(256) void packB_k(const float* __restrict__ W0,
                                               const float* __restrict__ W1,
                                               const float* __restrict__ Wn,
                                               const float* __restrict__ We,
                                               unsigned short* __restrict__ P0,
                                               unsigned short* __restrict__ P1,
                                               unsigned short* __restrict__ Pn,
                                               unsigned short* __restrict__ Pe)
{
    int idx = blockIdx.x * 256 + threadIdx.x;
    if (idx >= 49152) return;
    const float* S; unsigned short* D; int BN; int local;
    if (idx < 16384)      { S = W0; D = P0; BN = 128; local = idx; }
    else if (idx < 32768) { S = W1; D = P1; BN = 128; local = idx - 16384; }
    else if (idx < 40960) { S = Wn; D = Pn; BN = 64;  local = idx - 32768; }
    else                  { S = We; D = Pe; BN = 64;  local = idx - 40960; }
    int k = local / BN, nn = local % BN;
    D[(((k >> 3) * BN + nn) * 8) + (k & 7)] = f2bf(S[local]);
}

// ---------------- MFMA GEMM: A[n x 128]bf16 @ B[128 x BN] ------------------
// OUTF32: fp32 out + bias (projection heads); else bf16 out, no bias.
template<int BN, bool OUTF32>
__global__ __launch_bounds__(256) void gemm_mfma_k(const unsigned short* __restrict__ Ab,
                                                   const unsigned short* __restrict__ Bp,
                                                   const float* __restrict__ bias,
                                                   unsigned short* __restrict__ Cb,
                                                   float* __restrict__ Cf, int n)
{
    constexpr int WCn = BN / 64;        // wave-cols: 2 (BN=128) / 1 (BN=64)
    constexpr int WRn = 4 / WCn;        // wave-rows
    constexpr int ROWT = 4 / WRn;       // 16-row tiles per wave
    constexpr int APITCH = 144;         // bf16 units (pad 16 -> conflict-free b128)
    constexpr int BPITCH = BN + 2;      // entries per octet-row (pad 2 entries)

    __shared__ unsigned short As[64 * APITCH];
    __shared__ unsigned short Bs[16 * BPITCH * 8];

    const int t  = threadIdx.x;
    const int rb = blockIdx.x * 64;

    // stage A: 64 x 128 bf16 (guarded, zero-fill)
#pragma unroll
    for (int i = 0; i < 4; ++i) {
        int q = t + i * 256;            // 1024 float4s
        int r = q >> 4;
        int c = (q & 15) * 8;
        float4 v = make_float4(0.f, 0.f, 0.f, 0.f);
        int gr = rb + r;
        if (gr < n) v = *(const float4*)(Ab + (size_t)gr * 128 + c);
        *(float4*)(As + r * APITCH + c) = v;
    }
    // stage B: 16*BN octet entries (16B each), already packed in global
    constexpr int BE = 16 * BN;
#pragma unroll
    for (int i = 0; i < BE / 256; ++i) {
        int ge = t + i * 256;
        int o = ge / BN, nn = ge % BN;
        *(float4*)(Bs + ((size_t)o * BPITCH + nn) * 8) = *(const float4*)(Bp + (size_t)ge * 8);
    }
    __syncthreads();

    const int w = t >> 6, lane = t & 63;
    const int m = lane & 15, quad = lane >> 4;
    const int wc = w % WCn, wr = w / WCn;
    const int row0 = wr * (64 / WRn);
    const int col0 = wc * 64;

    f32x4 acc[ROWT][4];
#pragma unroll
    for (int rt = 0; rt < ROWT; ++rt)
#pragma unroll
        for (int c = 0; c < 4; ++c) acc[rt][c] = (f32x4){0.f, 0.f, 0.f, 0.f};

    s16x8 a[ROWT][4];
#pragma unroll
    for (int rt = 0; rt < ROWT; ++rt)
#pragma unroll
        for (int kk = 0; kk < 4; ++kk)
            a[rt][kk] = *(const s16x8*)(As + (row0 + rt * 16 + m) * APITCH + kk * 32 + quad * 8);

#pragma unroll
    for (int kk = 0; kk < 4; ++kk)
#pragma unroll
        for (int c = 0; c < 4; ++c) {
            s16x8 b = *(const s16x8*)(Bs + ((size_t)(kk * 4 + quad) * BPITCH + col0 + c * 16 + m) * 8);
#pragma unroll
            for (int rt = 0; rt < ROWT; ++rt)
                acc[rt][c] = __builtin_amdgcn_mfma_f32_16x16x32_bf16(a[rt][kk], b, acc[rt][c], 0, 0, 0);
        }

    // epilogue: C/D layout col=lane&15, row=quad*4+reg
#pragma unroll
    for (int rt = 0; rt < ROWT; ++rt)
#pragma unroll
        for (int c = 0; c < 4; ++c)
#pragma unroll
            for (int r = 0; r < 4; ++r) {
                int row = rb + row0 + rt * 16 + quad * 4 + r;
                int colg = col0 + c * 16 + m;
                if (row < n) {
                    float v = acc[rt][c][r];
                    if (OUTF32) Cf[(size_t)row * BN + colg] = v + bias[colg];
                    else        Cb[(size_t)row * 128 + colg] = f2bf(v);
                }
            }
}

// ---------------- attention logits (bf16 xl) -------------------------------
template<int H>
__global__ __launch_bounds__(256) void att_k(const unsigned short* __restrict__ xlb,
                                             const float* __restrict__ ats,
                                             const float* __restrict__ atd,
                                             float* __restrict__ a_s,
                                             float* __restrict__ a_d, int n)
{
    int node = (blockIdx.x * 256 + threadIdx.x) >> 6;
    int lane = threadIdx.x & 63;
    if (node >= n) return;
    int j = 2 * lane;
    unsigned u = *(const unsigned*)(xlb + (size_t)node * 128 + j);
    float vx = bflo(u), vy = bfhi(u);
    float ps = vx * ats[j] + vy * ats[j + 1];
    float pd = vx * atd[j] + vy * atd[j + 1];
    constexpr int GS = 64 / H;
#pragma unroll
    for (int off = 1; off < GS; off <<= 1) {
        ps += __shfl_xor(ps, off);
        pd += __shfl_xor(pd, off);
    }
    if ((lane & (GS - 1)) == 0) {
        int h = lane / GS;
        a_s[(size_t)node * H + h] = ps;
        a_d[(size_t)node * H + h] = pd;
    }
}

// ---------------- CSR build ------------------------------------------------
__global__ void zero_k(int* p, int n)
{
    int i = blockIdx.x * 256 + threadIdx.x;
    if (i < n) p[i] = 0;
}

__global__ void count_k(const int* __restrict__ ei, int* __restrict__ deg,
                        int E, int n)
{
    int e = blockIdx.x * 256 + threadIdx.x;
    if (e >= E + n) return;
    int d = (e < E) ? ei[E + e] : (e - E);
    atomicAdd(&deg[d], 1);
}

__global__ void scanA_k(const int* __restrict__ deg, int* __restrict__ excl,
                        int* __restrict__ bsum, int n)
{
    __shared__ int sm[256];
    int t = threadIdx.x, i = blockIdx.x * 256 + t;
    int v = (i < n) ? deg[i] : 0;
    sm[t] = v;
    __syncthreads();
    for (int off = 1; off < 256; off <<= 1) {
        int x = (t >= off) ? sm[t - off] : 0;
        __syncthreads();
        sm[t] += x;
        __syncthreads();
    }
    if (i < n) excl[i] = sm[t] - v;
    if (t == 255) bsum[blockIdx.x] = sm[t];
}

__global__ void scanB_k(const int* __restrict__ bsum, int* __restrict__ boff, int nb)
{
    __shared__ int sm[256];
    int t = threadIdx.x;
    int v = (t < nb) ? bsum[t] : 0;
    sm[t] = v;
    __syncthreads();
    for (int off = 1; off < 256; off <<= 1) {
        int x = (t >= off) ? sm[t - off] : 0;
        __syncthreads();
        sm[t] += x;
        __syncthreads();
    }
    if (t < nb) boff[t] = sm[t] - v;
}

__global__ void scanC_k(int* __restrict__ rowptr, const int* __restrict__ boff,
                        int* __restrict__ cursor, int n, int ET)
{
    int i = blockIdx.x * 256 + threadIdx.x;
    if (i < n) {
        int v = rowptr[i] + boff[i >> 8];
        rowptr[i] = v;
        cursor[i] = v;
    }
    if (i == n) rowptr[n] = ET;
}

__global__ void scatter_k(const int* __restrict__ ei, int* __restrict__ cursor,
                          int* __restrict__ col, int E, int n)
{
    int e = blockIdx.x * 256 + threadIdx.x;
    if (e >= E + n) return;
    int s = (e < E) ? ei[e]     : (e - E);
    int d = (e < E) ? ei[E + e] : (e - E);
    int pos = atomicAdd(&cursor[d], 1);
    col[pos] = s;
}

// ---------------- GAT aggregation: one wave per destination node -----------
// bf16 feature gather (4B/lane), shfl-batched indices, 8-deep load pipeline.
template<int H>
__global__ __launch_bounds__(256) void agg_k(const unsigned short* __restrict__ xlb,
                                             const float* __restrict__ a_s,
                                             const float* __restrict__ a_d,
                                             const int* __restrict__ rowptr,
                                             const int* __restrict__ col,
                                             const float* __restrict__ bias,
                                             unsigned short* __restrict__ outb, int n)
{
    int node = (blockIdx.x * 256 + threadIdx.x) >> 6;
    int lane = threadIdx.x & 63;
    if (node >= n) return;
    int h = (H == 1) ? 0 : (lane >> 4);
    float ad = a_d[(size_t)node * H + h];
    int p0 = rowptr[node], p1 = rowptr[node + 1];
    float accx = 0.f, accy = 0.f, den = 0.f;
    const unsigned short* xlj = xlb + 2 * lane;

    for (int base = p0; base < p1; base += 64) {
        int m = p1 - base;
        if (m > 64) m = 64;
        int cv = col[base + (lane < m ? lane : m - 1)];
        int j = 0;
        for (; j + 8 <= m; j += 8) {
            int s[8];
#pragma unroll
            for (int q = 0; q < 8; ++q) s[q] = __shfl(cv, j + q);
            float as[8];
            unsigned uv[8];
#pragma unroll
            for (int q = 0; q < 8; ++q) as[q] = a_s[(size_t)s[q] * H + h];
#pragma unroll
            for (int q = 0; q < 8; ++q) uv[q] = *(const unsigned*)(xlj + (size_t)s[q] * 128);
#pragma unroll
            for (int q = 0; q < 8; ++q) {
                float al = as[q] + ad;
                al = (al >= 0.f) ? al : LEAKY_SLOPE * al;
                float w = __expf(al);
                accx = fmaf(w, bflo(uv[q]), accx);
                accy = fmaf(w, bfhi(uv[q]), accy);
                den += w;
            }
        }
        int rem = m - j;
        if (rem > 0) {
            int s[8];
            float as[8];
            unsigned uv[8];
#pragma unroll
            for (int q = 0; q < 8; ++q) {
                int jj = (q < rem) ? (j + q) : j;
                s[q] = __shfl(cv, jj);
            }
#pragma unroll
            for (int q = 0; q < 8; ++q) as[q] = a_s[(size_t)s[q] * H + h];
#pragma unroll
            for (int q = 0; q < 8; ++q) uv[q] = *(const unsigned*)(xlj + (size_t)s[q] * 128);
#pragma unroll
            for (int q = 0; q < 8; ++q) {
                float al = as[q] + ad;
                al = (al >= 0.f) ? al : LEAKY_SLOPE * al;
                float w = (q < rem) ? __expf(al) : 0.f;
                accx = fmaf(w, bflo(uv[q]), accx);
                accy = fmaf(w, bfhi(uv[q]), accy);
                den += w;
            }
        }
    }

    float inv = 1.0f / (den + 1e-16f);
    int j = 2 * lane;
    float o0 = fmaxf(fmaf(accx, inv, bias[j]),     0.f);
    float o1 = fmaxf(fmaf(accy, inv, bias[j + 1]), 0.f);
    unsigned pk = (unsigned)f2bf(o0) | ((unsigned)f2bf(o1) << 16);
    *(unsigned*)(outb + (size_t)node * 128 + j) = pk;
}

// ---------------------------------------------------------------------------
extern "C" void kernel_launch(void* const* d_in, const int* in_sizes, int n_in,
                              void* d_out, int out_size, void* d_ws, size_t ws_size,
                              hipStream_t stream)
{
    const float* x   = (const float*)d_in[0];
    const int*   ei  = (const int*)d_in[1];
    const float* W0  = (const float*)d_in[2];
    const float* as0 = (const float*)d_in[3];
    const float* ad0 = (const float*)d_in[4];
    const float* b0  = (const float*)d_in[5];
    const float* W1  = (const float*)d_in[6];
    const float* as1 = (const float*)d_in[7];
    const float* ad1 = (const float*)d_in[8];
    const float* b1  = (const float*)d_in[9];
    const float* Wn  = (const float*)d_in[10];
    const float* bn  = (const float*)d_in[11];
    const float* We  = (const float*)d_in[12];
    const float* be  = (const float*)d_in[13];

    const int n  = in_sizes[0] / 128;
    const int E  = in_sizes[1] / 2;
    const int ET = E + n;
    float* out = (float*)d_out;

    char* w = (char*)d_ws;
    auto carve = [&](size_t bytes) -> void* {
        void* p = (void*)w;
        w += (bytes + 255) & ~(size_t)255;
        return p;
    };
    unsigned short* xb  = (unsigned short*)carve((size_t)n * 128 * 2);  // bf16 x
    unsigned short* xlb = (unsigned short*)carve((size_t)n * 128 * 2);  // bf16 xl
    unsigned short* hb  = (unsigned short*)carve((size_t)n * 128 * 2);  // bf16 h0/h1
    float* a_s  = (float*)carve((size_t)n * 4 * 4);
    float* a_d  = (float*)carve((size_t)n * 4 * 4);
    int*   deg  = (int*)carve((size_t)n * 4);
    int*   rowp = (int*)carve((size_t)(n + 1) * 4);
    int*   curs = (int*)carve((size_t)n * 4);
    int*   colv = (int*)carve((size_t)ET * 4);
    int*   bsum = (int*)carve(1024);
    int*   boff = (int*)carve(1024);
    unsigned short* P0 = (unsigned short*)carve(16384 * 2);
    unsigned short* P1 = (unsigned short*)carve(16384 * 2);
    unsigned short* Pn = (unsigned short*)carve(8192 * 2);
    unsigned short* Pe = (unsigned short*)carve(8192 * 2);

    const int gN64 = (n + 63) / 64;
    const int gWv  = (n + 3) / 4;
    const int gE   = (ET + 255) / 256;
    const int NB   = (n + 255) / 256;

    // ---- casts/packs ----
    cast4_k<<<(n * 32 + 255) / 256, 256, 0, stream>>>(x, xb, n * 32);
    packB_k<<<192, 256, 0, stream>>>(W0, W1, Wn, We, P0, P1, Pn, Pe);

    // ---- CSR by destination (shared by both layers) ----
    zero_k   <<<NB, 256, 0, stream>>>(deg, n);
    count_k  <<<gE, 256, 0, stream>>>(ei, deg, E, n);
    scanA_k  <<<NB, 256, 0, stream>>>(deg, rowp, bsum, n);
    scanB_k  <<<1, 256, 0, stream>>>(bsum, boff, NB);
    scanC_k  <<<(n + 256) / 256, 256, 0, stream>>>(rowp, boff, curs, n, ET);
    scatter_k<<<gE, 256, 0, stream>>>(ei, curs, colv, E, n);

    // ---- layer 0: H=4, C=32 ----
    gemm_mfma_k<128, false><<<gN64, 256, 0, stream>>>(xb, P0, nullptr, xlb, nullptr, n);
    att_k<4><<<gWv, 256, 0, stream>>>(xlb, as0, ad0, a_s, a_d, n);
    agg_k<4><<<gWv, 256, 0, stream>>>(xlb, a_s, a_d, rowp, colv, b0, hb, n);

    // ---- layer 1: H=1, C=128 ----
    gemm_mfma_k<128, false><<<gN64, 256, 0, stream>>>(hb, P1, nullptr, xlb, nullptr, n);
    att_k<1><<<gWv, 256, 0, stream>>>(xlb, as1, ad1, a_s, a_d, n);
    agg_k<1><<<gWv, 256, 0, stream>>>(xlb, a_s, a_d, rowp, colv, b1, hb, n);

    // ---- projection heads: out = [h_ego || h_neighbor] ----
    gemm_mfma_k<64, true><<<gN64, 256, 0, stream>>>(xb, Pe, be, nullptr, out, n);
    gemm_mfma_k<64, true><<<gN64, 256, 0, stream>>>(hb, Pn, bn, nullptr, out + (size_t)n * 64, n);
}

// Round 4
// 287.893 us; speedup vs baseline: 1.7093x; 1.1244x over previous
//
#include <hip/hip_runtime.h>

// ---------------------------------------------------------------------------
// GAT GNN: h0 = relu(GAT0(x)); h1 = relu(GAT1(h0));
// out = [x@We+be  ||  h1@Wn+bn]
// R3: bf16 features + MFMA GEMMs.
// R4: CSR build restructure — single fused atomic pass (slot assignment,
//     cursor padded to 1 counter / 64B line), atomic-free scatter phase 2.
//     (was: count_k 850k atomics + scatter_k 850k atomic-returns, ~100us)
// ---------------------------------------------------------------------------

#define LEAKY_SLOPE 0.2f

typedef __attribute__((ext_vector_type(8))) short s16x8;
typedef __attribute__((ext_vector_type(4))) float f32x4;

static __device__ __forceinline__ unsigned short f2bf(float f)
{
    unsigned x = __float_as_uint(f);
    unsigned r = (x + 0x7fffu + ((x >> 16) & 1u)) >> 16;   // RNE
    return (unsigned short)r;
}
static __device__ __forceinline__ float bfhi(unsigned u) { return __uint_as_float(u & 0xffff0000u); }
static __device__ __forceinline__ float bflo(unsigned u) { return __uint_as_float(u << 16); }

// ---------------- fp32 -> bf16 cast (x) ------------------------------------
__global__ __launch_bounds__(256) void cast4_k(const float* __restrict__ src,
                                               unsigned short* __restrict__ dst, int n4)
{
    int i = blockIdx.x * 256 + threadIdx.x;
    if (i >= n4) return;
    float4 v = ((const float4*)src)[i];
    ushort4 o;
    o.x = f2bf(v.x); o.y = f2bf(v.y); o.z = f2bf(v.z); o.w = f2bf(v.w);
    ((ushort4*)dst)[i] = o;
}

// ---------------- weight pack: fp32 [128 x BN] -> bf16 octet layout --------
__global__ __launch_bounds__(256) void packB_k(const float* __restrict__ W0,
                                               const float* __restrict__ W1,
                                               const float* __restrict__ Wn,
                                               const float* __restrict__ We,
                                               unsigned short* __restrict__ P0,
                                               unsigned short* __restrict__ P1,
                                               unsigned short* __restrict__ Pn,
                                               unsigned short* __restrict__ Pe)
{
    int idx = blockIdx.x * 256 + threadIdx.x;
    if (idx >= 49152) return;
    const float* S; unsigned short* D; int BN; int local;
    if (idx < 16384)      { S = W0; D = P0; BN = 128; local = idx; }
    else if (idx < 32768) { S = W1; D = P1; BN = 128; local = idx - 16384; }
    else if (idx < 40960) { S = Wn; D = Pn; BN = 64;  local = idx - 32768; }
    else                  { S = We; D = Pe; BN = 64;  local = idx - 40960; }
    int k = local / BN, nn = local % BN;
    D[(((k >> 3) * BN + nn) * 8) + (k & 7)] = f2bf(S[local]);
}

// ---------------- MFMA GEMM: A[n x 128]bf16 @ B[128 x BN] ------------------
template<int BN, bool OUTF32>
__global__ __launch_bounds__(256) void gemm_mfma_k(const unsigned short* __restrict__ Ab,
                                                   const unsigned short* __restrict__ Bp,
                                                   const float* __restrict__ bias,
                                                   unsigned short* __restrict__ Cb,
                                                   float* __restrict__ Cf, int n)
{
    constexpr int WCn = BN / 64;
    constexpr int WRn = 4 / WCn;
    constexpr int ROWT = 4 / WRn;
    constexpr int APITCH = 144;
    constexpr int BPITCH = BN + 2;

    __shared__ unsigned short As[64 * APITCH];
    __shared__ unsigned short Bs[16 * BPITCH * 8];

    const int t  = threadIdx.x;
    const int rb = blockIdx.x * 64;

#pragma unroll
    for (int i = 0; i < 4; ++i) {
        int q = t + i * 256;
        int r = q >> 4;
        int c = (q & 15) * 8;
        float4 v = make_float4(0.f, 0.f, 0.f, 0.f);
        int gr = rb + r;
        if (gr < n) v = *(const float4*)(Ab + (size_t)gr * 128 + c);
        *(float4*)(As + r * APITCH + c) = v;
    }
    constexpr int BE = 16 * BN;
#pragma unroll
    for (int i = 0; i < BE / 256; ++i) {
        int ge = t + i * 256;
        int o = ge / BN, nn = ge % BN;
        *(float4*)(Bs + ((size_t)o * BPITCH + nn) * 8) = *(const float4*)(Bp + (size_t)ge * 8);
    }
    __syncthreads();

    const int w = t >> 6, lane = t & 63;
    const int m = lane & 15, quad = lane >> 4;
    const int wc = w % WCn, wr = w / WCn;
    const int row0 = wr * (64 / WRn);
    const int col0 = wc * 64;

    f32x4 acc[ROWT][4];
#pragma unroll
    for (int rt = 0; rt < ROWT; ++rt)
#pragma unroll
        for (int c = 0; c < 4; ++c) acc[rt][c] = (f32x4){0.f, 0.f, 0.f, 0.f};

    s16x8 a[ROWT][4];
#pragma unroll
    for (int rt = 0; rt < ROWT; ++rt)
#pragma unroll
        for (int kk = 0; kk < 4; ++kk)
            a[rt][kk] = *(const s16x8*)(As + (row0 + rt * 16 + m) * APITCH + kk * 32 + quad * 8);

#pragma unroll
    for (int kk = 0; kk < 4; ++kk)
#pragma unroll
        for (int c = 0; c < 4; ++c) {
            s16x8 b = *(const s16x8*)(Bs + ((size_t)(kk * 4 + quad) * BPITCH + col0 + c * 16 + m) * 8);
#pragma unroll
            for (int rt = 0; rt < ROWT; ++rt)
                acc[rt][c] = __builtin_amdgcn_mfma_f32_16x16x32_bf16(a[rt][kk], b, acc[rt][c], 0, 0, 0);
        }

#pragma unroll
    for (int rt = 0; rt < ROWT; ++rt)
#pragma unroll
        for (int c = 0; c < 4; ++c)
#pragma unroll
            for (int r = 0; r < 4; ++r) {
                int row = rb + row0 + rt * 16 + quad * 4 + r;
                int colg = col0 + c * 16 + m;
                if (row < n) {
                    float v = acc[rt][c][r];
                    if (OUTF32) Cf[(size_t)row * BN + colg] = v + bias[colg];
                    else        Cb[(size_t)row * 128 + colg] = f2bf(v);
                }
            }
}

// ---------------- attention logits (bf16 xl) -------------------------------
template<int H>
__global__ __launch_bounds__(256) void att_k(const unsigned short* __restrict__ xlb,
                                             const float* __restrict__ ats,
                                             const float* __restrict__ atd,
                                             float* __restrict__ a_s,
                                             float* __restrict__ a_d, int n)
{
    int node = (blockIdx.x * 256 + threadIdx.x) >> 6;
    int lane = threadIdx.x & 63;
    if (node >= n) return;
    int j = 2 * lane;
    unsigned u = *(const unsigned*)(xlb + (size_t)node * 128 + j);
    float vx = bflo(u), vy = bfhi(u);
    float ps = vx * ats[j] + vy * ats[j + 1];
    float pd = vx * atd[j] + vy * atd[j + 1];
    constexpr int GS = 64 / H;
#pragma unroll
    for (int off = 1; off < GS; off <<= 1) {
        ps += __shfl_xor(ps, off);
        pd += __shfl_xor(pd, off);
    }
    if ((lane & (GS - 1)) == 0) {
        int h = lane / GS;
        a_s[(size_t)node * H + h] = ps;
        a_d[(size_t)node * H + h] = pd;
    }
}

// ---------------- CSR build (R4) -------------------------------------------
// cursP: one counter per 64B line (stride 16 ints) to spread atomic RMWs.
__global__ void zero_k(int* p, int n)
{
    int i = blockIdx.x * 256 + threadIdx.x;
    if (i < n) p[i] = 0;
}

// Phase 1: fused count + slot assignment. cursP[d*16] ends as deg[d].
__global__ void scat1_k(const int* __restrict__ ei, int* __restrict__ cursP,
                        int* __restrict__ slot, int E, int n)
{
    int e = blockIdx.x * 256 + threadIdx.x;
    if (e >= E + n) return;
    int d = (e < E) ? ei[E + e] : (e - E);   // self-loop dst = node id
    slot[e] = atomicAdd(&cursP[d << 4], 1);
}

// scans read the padded cursor (stride 16)
__global__ void scanA_k(const int* __restrict__ cursP, int* __restrict__ excl,
                        int* __restrict__ bsum, int n)
{
    __shared__ int sm[256];
    int t = threadIdx.x, i = blockIdx.x * 256 + t;
    int v = (i < n) ? cursP[i << 4] : 0;
    sm[t] = v;
    __syncthreads();
    for (int off = 1; off < 256; off <<= 1) {
        int x = (t >= off) ? sm[t - off] : 0;
        __syncthreads();
        sm[t] += x;
        __syncthreads();
    }
    if (i < n) excl[i] = sm[t] - v;
    if (t == 255) bsum[blockIdx.x] = sm[t];
}

__global__ void scanB_k(const int* __restrict__ bsum, int* __restrict__ boff, int nb)
{
    __shared__ int sm[256];
    int t = threadIdx.x;
    int v = (t < nb) ? bsum[t] : 0;
    sm[t] = v;
    __syncthreads();
    for (int off = 1; off < 256; off <<= 1) {
        int x = (t >= off) ? sm[t - off] : 0;
        __syncthreads();
        sm[t] += x;
        __syncthreads();
    }
    if (t < nb) boff[t] = sm[t] - v;
}

__global__ void scanC_k(int* __restrict__ rowptr, const int* __restrict__ boff,
                        int n, int ET)
{
    int i = blockIdx.x * 256 + threadIdx.x;
    if (i < n) rowptr[i] += boff[i >> 8];
    if (i == n) rowptr[n] = ET;
}

// Phase 2: atomic-free scatter using precomputed slots.
__global__ void scat2_k(const int* __restrict__ ei, const int* __restrict__ rowptr,
                        const int* __restrict__ slot, int* __restrict__ col,
                        int E, int n)
{
    int e = blockIdx.x * 256 + threadIdx.x;
    if (e >= E + n) return;
    int s = (e < E) ? ei[e]     : (e - E);
    int d = (e < E) ? ei[E + e] : (e - E);
    col[rowptr[d] + slot[e]] = s;
}

// ---------------- GAT aggregation: one wave per destination node -----------
template<int H>
__global__ __launch_bounds__(256) void agg_k(const unsigned short* __restrict__ xlb,
                                             const float* __restrict__ a_s,
                                             const float* __restrict__ a_d,
                                             const int* __restrict__ rowptr,
                                             const int* __restrict__ col,
                                             const float* __restrict__ bias,
                                             unsigned short* __restrict__ outb, int n)
{
    int node = (blockIdx.x * 256 + threadIdx.x) >> 6;
    int lane = threadIdx.x & 63;
    if (node >= n) return;
    int h = (H == 1) ? 0 : (lane >> 4);
    float ad = a_d[(size_t)node * H + h];
    int p0 = rowptr[node], p1 = rowptr[node + 1];
    float accx = 0.f, accy = 0.f, den = 0.f;
    const unsigned short* xlj = xlb + 2 * lane;

    for (int base = p0; base < p1; base += 64) {
        int m = p1 - base;
        if (m > 64) m = 64;
        int cv = col[base + (lane < m ? lane : m - 1)];
        int j = 0;
        for (; j + 8 <= m; j += 8) {
            int s[8];
#pragma unroll
            for (int q = 0; q < 8; ++q) s[q] = __shfl(cv, j + q);
            float as[8];
            unsigned uv[8];
#pragma unroll
            for (int q = 0; q < 8; ++q) as[q] = a_s[(size_t)s[q] * H + h];
#pragma unroll
            for (int q = 0; q < 8; ++q) uv[q] = *(const unsigned*)(xlj + (size_t)s[q] * 128);
#pragma unroll
            for (int q = 0; q < 8; ++q) {
                float al = as[q] + ad;
                al = (al >= 0.f) ? al : LEAKY_SLOPE * al;
                float w = __expf(al);
                accx = fmaf(w, bflo(uv[q]), accx);
                accy = fmaf(w, bfhi(uv[q]), accy);
                den += w;
            }
        }
        int rem = m - j;
        if (rem > 0) {
            int s[8];
            float as[8];
            unsigned uv[8];
#pragma unroll
            for (int q = 0; q < 8; ++q) {
                int jj = (q < rem) ? (j + q) : j;
                s[q] = __shfl(cv, jj);
            }
#pragma unroll
            for (int q = 0; q < 8; ++q) as[q] = a_s[(size_t)s[q] * H + h];
#pragma unroll
            for (int q = 0; q < 8; ++q) uv[q] = *(const unsigned*)(xlj + (size_t)s[q] * 128);
#pragma unroll
            for (int q = 0; q < 8; ++q) {
                float al = as[q] + ad;
                al = (al >= 0.f) ? al : LEAKY_SLOPE * al;
                float w = (q < rem) ? __expf(al) : 0.f;
                accx = fmaf(w, bflo(uv[q]), accx);
                accy = fmaf(w, bfhi(uv[q]), accy);
                den += w;
            }
        }
    }

    float inv = 1.0f / (den + 1e-16f);
    int j = 2 * lane;
    float o0 = fmaxf(fmaf(accx, inv, bias[j]),     0.f);
    float o1 = fmaxf(fmaf(accy, inv, bias[j + 1]), 0.f);
    unsigned pk = (unsigned)f2bf(o0) | ((unsigned)f2bf(o1) << 16);
    *(unsigned*)(outb + (size_t)node * 128 + j) = pk;
}

// ---------------------------------------------------------------------------
extern "C" void kernel_launch(void* const* d_in, const int* in_sizes, int n_in,
                              void* d_out, int out_size, void* d_ws, size_t ws_size,
                              hipStream_t stream)
{
    const float* x   = (const float*)d_in[0];
    const int*   ei  = (const int*)d_in[1];
    const float* W0  = (const float*)d_in[2];
    const float* as0 = (const float*)d_in[3];
    const float* ad0 = (const float*)d_in[4];
    const float* b0  = (const float*)d_in[5];
    const float* W1  = (const float*)d_in[6];
    const float* as1 = (const float*)d_in[7];
    const float* ad1 = (const float*)d_in[8];
    const float* b1  = (const float*)d_in[9];
    const float* Wn  = (const float*)d_in[10];
    const float* bn  = (const float*)d_in[11];
    const float* We  = (const float*)d_in[12];
    const float* be  = (const float*)d_in[13];

    const int n  = in_sizes[0] / 128;
    const int E  = in_sizes[1] / 2;
    const int ET = E + n;
    float* out = (float*)d_out;

    char* w = (char*)d_ws;
    auto carve = [&](size_t bytes) -> void* {
        void* p = (void*)w;
        w += (bytes + 255) & ~(size_t)255;
        return p;
    };
    unsigned short* xb  = (unsigned short*)carve((size_t)n * 128 * 2);
    unsigned short* xlb = (unsigned short*)carve((size_t)n * 128 * 2);
    unsigned short* hb  = (unsigned short*)carve((size_t)n * 128 * 2);
    float* a_s  = (float*)carve((size_t)n * 4 * 4);
    float* a_d  = (float*)carve((size_t)n * 4 * 4);
    int*   curs = (int*)carve((size_t)n * 16 * 4);     // padded: 1 counter / 64B
    int*   rowp = (int*)carve((size_t)(n + 1) * 4);
    int*   slot = (int*)carve((size_t)ET * 4);
    int*   colv = (int*)carve((size_t)ET * 4);
    int*   bsum = (int*)carve(1024);
    int*   boff = (int*)carve(1024);
    unsigned short* P0 = (unsigned short*)carve(16384 * 2);
    unsigned short* P1 = (unsigned short*)carve(16384 * 2);
    unsigned short* Pn = (unsigned short*)carve(8192 * 2);
    unsigned short* Pe = (unsigned short*)carve(8192 * 2);

    const int gN64 = (n + 63) / 64;
    const int gWv  = (n + 3) / 4;
    const int gE   = (ET + 255) / 256;
    const int NB   = (n + 255) / 256;

    // ---- casts/packs ----
    cast4_k<<<(n * 32 + 255) / 256, 256, 0, stream>>>(x, xb, n * 32);
    packB_k<<<192, 256, 0, stream>>>(W0, W1, Wn, We, P0, P1, Pn, Pe);

    // ---- CSR by destination (shared by both layers) ----
    zero_k <<<(n * 16 + 255) / 256, 256, 0, stream>>>(curs, n * 16);
    scat1_k<<<gE, 256, 0, stream>>>(ei, curs, slot, E, n);
    scanA_k<<<NB, 256, 0, stream>>>(curs, rowp, bsum, n);
    scanB_k<<<1, 256, 0, stream>>>(bsum, boff, NB);
    scanC_k<<<(n + 256) / 256, 256, 0, stream>>>(rowp, boff, n, ET);
    scat2_k<<<gE, 256, 0, stream>>>(ei, rowp, slot, colv, E, n);

    // ---- layer 0: H=4, C=32 ----
    gemm_mfma_k<128, false><<<gN64, 256, 0, stream>>>(xb, P0, nullptr, xlb, nullptr, n);
    att_k<4><<<gWv, 256, 0, stream>>>(xlb, as0, ad0, a_s, a_d, n);
    agg_k<4><<<gWv, 256, 0, stream>>>(xlb, a_s, a_d, rowp, colv, b0, hb, n);

    // ---- layer 1: H=1, C=128 ----
    gemm_mfma_k<128, false><<<gN64, 256, 0, stream>>>(hb, P1, nullptr, xlb, nullptr, n);
    att_k<1><<<gWv, 256, 0, stream>>>(xlb, as1, ad1, a_s, a_d, n);
    agg_k<1><<<gWv, 256, 0, stream>>>(xlb, a_s, a_d, rowp, colv, b1, hb, n);

    // ---- projection heads: out = [h_ego || h_neighbor] ----
    gemm_mfma_k<64, true><<<gN64, 256, 0, stream>>>(xb, Pe, be, nullptr, out, n);
    gemm_mfma_k<64, true><<<gN64, 256, 0, stream>>>(hb, Pn, bn, nullptr, out + (size_t)n * 64, n);
}

// Round 5
// 278.653 us; speedup vs baseline: 1.7659x; 1.0332x over previous
//
#include <hip/hip_runtime.h>

// ---------------------------------------------------------------------------
// GAT GNN: h0 = relu(GAT0(x)); h1 = relu(GAT1(h0));
// out = [x@We+be  ||  h1@Wn+bn]
// R3: bf16 features + MFMA GEMMs.  R4: low-contention 2-phase CSR build.
// R5: att logits fused into GEMM epilogue (fp32 acc -> per-head dots in-wave
//     for H=4, LDS cross-wave combine for H=1); cast+pack+zero fused (prep_k).
//     16 -> 12 dispatches, -25.6 MB xlb re-read.
// ---------------------------------------------------------------------------

#define LEAKY_SLOPE 0.2f

typedef __attribute__((ext_vector_type(8))) short s16x8;
typedef __attribute__((ext_vector_type(4))) float f32x4;

static __device__ __forceinline__ unsigned short f2bf(float f)
{
    unsigned x = __float_as_uint(f);
    unsigned r = (x + 0x7fffu + ((x >> 16) & 1u)) >> 16;   // RNE
    return (unsigned short)r;
}
static __device__ __forceinline__ float bfhi(unsigned u) { return __uint_as_float(u & 0xffff0000u); }
static __device__ __forceinline__ float bflo(unsigned u) { return __uint_as_float(u << 16); }

// ---------------- prep: cast x->bf16, pack 4 weight mats, zero cursors -----
__global__ __launch_bounds__(256) void prep_k(const float* __restrict__ x,
                                              const float* __restrict__ W0,
                                              const float* __restrict__ W1,
                                              const float* __restrict__ Wn,
                                              const float* __restrict__ We,
                                              unsigned short* __restrict__ xb,
                                              unsigned short* __restrict__ P0,
                                              unsigned short* __restrict__ P1,
                                              unsigned short* __restrict__ Pn,
                                              unsigned short* __restrict__ Pe,
                                              int* __restrict__ curs, int n)
{
    int gid = blockIdx.x * 256 + threadIdx.x;
    int nc = n * 32;                       // float4 count of x
    if (gid < nc) {
        float4 v = ((const float4*)x)[gid];
        ushort4 o;
        o.x = f2bf(v.x); o.y = f2bf(v.y); o.z = f2bf(v.z); o.w = f2bf(v.w);
        ((ushort4*)xb)[gid] = o;
    } else if (gid < nc + 49152) {
        int idx = gid - nc;
        const float* S; unsigned short* D; int BN; int local;
        if (idx < 16384)      { S = W0; D = P0; BN = 128; local = idx; }
        else if (idx < 32768) { S = W1; D = P1; BN = 128; local = idx - 16384; }
        else if (idx < 40960) { S = Wn; D = Pn; BN = 64;  local = idx - 32768; }
        else                  { S = We; D = Pe; BN = 64;  local = idx - 40960; }
        int k = local / BN, nn = local % BN;
        D[(((k >> 3) * BN + nn) * 8) + (k & 7)] = f2bf(S[local]);
    } else if (gid < nc + 49152 + n * 16) {
        curs[gid - nc - 49152] = 0;
    }
}

// ---------------- MFMA GEMM + fused attention logits -----------------------
// HATT=0: plain (heads, fp32 out + bias). HATT=4: layer0 logits. HATT=1: layer1.
template<int BN, int HATT, bool OUTF32>
__global__ __launch_bounds__(256) void gemm_mfma_k(const unsigned short* __restrict__ Ab,
                                                   const unsigned short* __restrict__ Bp,
                                                   const float* __restrict__ bias,
                                                   unsigned short* __restrict__ Cb,
                                                   float* __restrict__ Cf,
                                                   const float* __restrict__ ats,
                                                   const float* __restrict__ atd,
                                                   float* __restrict__ a_s,
                                                   float* __restrict__ a_d, int n)
{
    constexpr int WCn = BN / 64;
    constexpr int WRn = 4 / WCn;
    constexpr int ROWT = 4 / WRn;
    constexpr int APITCH = 144;
    constexpr int BPITCH = BN + 2;

    __shared__ unsigned short As[64 * APITCH];
    __shared__ unsigned short Bs[16 * BPITCH * 8];
    __shared__ float smS[64][2], smD[64][2];       // HATT==1 combine (1 KB)

    const int t  = threadIdx.x;
    const int rb = blockIdx.x * 64;

#pragma unroll
    for (int i = 0; i < 4; ++i) {
        int q = t + i * 256;
        int r = q >> 4;
        int c = (q & 15) * 8;
        float4 v = make_float4(0.f, 0.f, 0.f, 0.f);
        int gr = rb + r;
        if (gr < n) v = *(const float4*)(Ab + (size_t)gr * 128 + c);
        *(float4*)(As + r * APITCH + c) = v;
    }
    constexpr int BE = 16 * BN;
#pragma unroll
    for (int i = 0; i < BE / 256; ++i) {
        int ge = t + i * 256;
        int o = ge / BN, nn = ge % BN;
        *(float4*)(Bs + ((size_t)o * BPITCH + nn) * 8) = *(const float4*)(Bp + (size_t)ge * 8);
    }
    __syncthreads();

    const int w = t >> 6, lane = t & 63;
    const int m = lane & 15, quad = lane >> 4;
    const int wc = w % WCn, wr = w / WCn;
    const int row0 = wr * (64 / WRn);
    const int col0 = wc * 64;

    f32x4 acc[ROWT][4];
#pragma unroll
    for (int rt = 0; rt < ROWT; ++rt)
#pragma unroll
        for (int c = 0; c < 4; ++c) acc[rt][c] = (f32x4){0.f, 0.f, 0.f, 0.f};

    s16x8 a[ROWT][4];
#pragma unroll
    for (int rt = 0; rt < ROWT; ++rt)
#pragma unroll
        for (int kk = 0; kk < 4; ++kk)
            a[rt][kk] = *(const s16x8*)(As + (row0 + rt * 16 + m) * APITCH + kk * 32 + quad * 8);

#pragma unroll
    for (int kk = 0; kk < 4; ++kk)
#pragma unroll
        for (int c = 0; c < 4; ++c) {
            s16x8 b = *(const s16x8*)(Bs + ((size_t)(kk * 4 + quad) * BPITCH + col0 + c * 16 + m) * 8);
#pragma unroll
            for (int rt = 0; rt < ROWT; ++rt)
                acc[rt][c] = __builtin_amdgcn_mfma_f32_16x16x32_bf16(a[rt][kk], b, acc[rt][c], 0, 0, 0);
        }

    // ---- C store (C/D layout: col=lane&15, row=quad*4+reg) ----
#pragma unroll
    for (int rt = 0; rt < ROWT; ++rt)
#pragma unroll
        for (int c = 0; c < 4; ++c)
#pragma unroll
            for (int r = 0; r < 4; ++r) {
                int row = rb + row0 + rt * 16 + quad * 4 + r;
                int colg = col0 + c * 16 + m;
                if (row < n) {
                    float v = acc[rt][c][r];
                    if (OUTF32) Cf[(size_t)row * BN + colg] = v + bias[colg];
                    else        Cb[(size_t)row * 128 + colg] = f2bf(v);
                }
            }

    // ---- fused attention logits ----
    if (HATT == 4) {
        // wave's 64 cols = heads 2wc, 2wc+1 (32 ch each); dot completes in-wave
        float atsv[4], atdv[4];
#pragma unroll
        for (int c = 0; c < 4; ++c) {
            atsv[c] = ats[col0 + c * 16 + m];
            atdv[c] = atd[col0 + c * 16 + m];
        }
#pragma unroll
        for (int rt = 0; rt < ROWT; ++rt)
#pragma unroll
            for (int r = 0; r < 4; ++r)
#pragma unroll
                for (int hb = 0; hb < 2; ++hb) {
                    float ps = acc[rt][2*hb][r] * atsv[2*hb] + acc[rt][2*hb+1][r] * atsv[2*hb+1];
                    float pd = acc[rt][2*hb][r] * atdv[2*hb] + acc[rt][2*hb+1][r] * atdv[2*hb+1];
#pragma unroll
                    for (int off = 1; off < 16; off <<= 1) {
                        ps += __shfl_xor(ps, off);
                        pd += __shfl_xor(pd, off);
                    }
                    int row = rb + row0 + rt * 16 + quad * 4 + r;
                    if (m == 0 && row < n) {
                        a_s[(size_t)row * 4 + 2*wc + hb] = ps;
                        a_d[(size_t)row * 4 + 2*wc + hb] = pd;
                    }
                }
    }
    if (HATT == 1) {
        // dot spans both wave-cols -> LDS combine over wc
        float atsv[4], atdv[4];
#pragma unroll
        for (int c = 0; c < 4; ++c) {
            atsv[c] = ats[col0 + c * 16 + m];
            atdv[c] = atd[col0 + c * 16 + m];
        }
#pragma unroll
        for (int rt = 0; rt < ROWT; ++rt)
#pragma unroll
            for (int r = 0; r < 4; ++r) {
                float ps = 0.f, pd = 0.f;
#pragma unroll
                for (int c = 0; c < 4; ++c) {
                    ps = fmaf(acc[rt][c][r], atsv[c], ps);
                    pd = fmaf(acc[rt][c][r], atdv[c], pd);
                }
#pragma unroll
                for (int off = 1; off < 16; off <<= 1) {
                    ps += __shfl_xor(ps, off);
                    pd += __shfl_xor(pd, off);
                }
                int lrow = row0 + rt * 16 + quad * 4 + r;
                if (m == 0) { smS[lrow][wc] = ps; smD[lrow][wc] = pd; }
            }
        __syncthreads();
        if (t < 64) {
            int row = rb + t;
            if (row < n) {
                a_s[row] = smS[t][0] + smS[t][1];
                a_d[row] = smD[t][0] + smD[t][1];
            }
        }
    }
}

// ---------------- CSR build ------------------------------------------------
// Phase 1: fused count + slot assignment; cursP padded 1 counter / 64B line.
__global__ void scat1_k(const int* __restrict__ ei, int* __restrict__ cursP,
                        int* __restrict__ slot, int E, int n)
{
    int e = blockIdx.x * 256 + threadIdx.x;
    if (e >= E + n) return;
    int d = (e < E) ? ei[E + e] : (e - E);   // self-loop dst = node id
    slot[e] = atomicAdd(&cursP[d << 4], 1);
}

__global__ void scanA_k(const int* __restrict__ cursP, int* __restrict__ excl,
                        int* __restrict__ bsum, int n)
{
    __shared__ int sm[256];
    int t = threadIdx.x, i = blockIdx.x * 256 + t;
    int v = (i < n) ? cursP[i << 4] : 0;
    sm[t] = v;
    __syncthreads();
    for (int off = 1; off < 256; off <<= 1) {
        int x = (t >= off) ? sm[t - off] : 0;
        __syncthreads();
        sm[t] += x;
        __syncthreads();
    }
    if (i < n) excl[i] = sm[t] - v;
    if (t == 255) bsum[blockIdx.x] = sm[t];
}

__global__ void scanB_k(const int* __restrict__ bsum, int* __restrict__ boff, int nb)
{
    __shared__ int sm[256];
    int t = threadIdx.x;
    int v = (t < nb) ? bsum[t] : 0;
    sm[t] = v;
    __syncthreads();
    for (int off = 1; off < 256; off <<= 1) {
        int x = (t >= off) ? sm[t - off] : 0;
        __syncthreads();
        sm[t] += x;
        __syncthreads();
    }
    if (t < nb) boff[t] = sm[t] - v;
}

__global__ void scanC_k(int* __restrict__ rowptr, const int* __restrict__ boff,
                        int n, int ET)
{
    int i = blockIdx.x * 256 + threadIdx.x;
    if (i < n) rowptr[i] += boff[i >> 8];
    if (i == n) rowptr[n] = ET;
}

// Phase 2: atomic-free scatter using precomputed slots.
__global__ void scat2_k(const int* __restrict__ ei, const int* __restrict__ rowptr,
                        const int* __restrict__ slot, int* __restrict__ col,
                        int E, int n)
{
    int e = blockIdx.x * 256 + threadIdx.x;
    if (e >= E + n) return;
    int s = (e < E) ? ei[e]     : (e - E);
    int d = (e < E) ? ei[E + e] : (e - E);
    col[rowptr[d] + slot[e]] = s;
}

// ---------------- GAT aggregation: one wave per destination node -----------
template<int H>
__global__ __launch_bounds__(256) void agg_k(const unsigned short* __restrict__ xlb,
                                             const float* __restrict__ a_s,
                                             const float* __restrict__ a_d,
                                             const int* __restrict__ rowptr,
                                             const int* __restrict__ col,
                                             const float* __restrict__ bias,
                                             unsigned short* __restrict__ outb, int n)
{
    int node = (blockIdx.x * 256 + threadIdx.x) >> 6;
    int lane = threadIdx.x & 63;
    if (node >= n) return;
    int h = (H == 1) ? 0 : (lane >> 4);
    float ad = a_d[(size_t)node * H + h];
    int p0 = rowptr[node], p1 = rowptr[node + 1];
    float accx = 0.f, accy = 0.f, den = 0.f;
    const unsigned short* xlj = xlb + 2 * lane;

    for (int base = p0; base < p1; base += 64) {
        int m = p1 - base;
        if (m > 64) m = 64;
        int cv = col[base + (lane < m ? lane : m - 1)];
        int j = 0;
        for (; j + 8 <= m; j += 8) {
            int s[8];
#pragma unroll
            for (int q = 0; q < 8; ++q) s[q] = __shfl(cv, j + q);
            float as[8];
            unsigned uv[8];
#pragma unroll
            for (int q = 0; q < 8; ++q) as[q] = a_s[(size_t)s[q] * H + h];
#pragma unroll
            for (int q = 0; q < 8; ++q) uv[q] = *(const unsigned*)(xlj + (size_t)s[q] * 128);
#pragma unroll
            for (int q = 0; q < 8; ++q) {
                float al = as[q] + ad;
                al = (al >= 0.f) ? al : LEAKY_SLOPE * al;
                float w = __expf(al);
                accx = fmaf(w, bflo(uv[q]), accx);
                accy = fmaf(w, bfhi(uv[q]), accy);
                den += w;
            }
        }
        int rem = m - j;
        if (rem > 0) {
            int s[8];
            float as[8];
            unsigned uv[8];
#pragma unroll
            for (int q = 0; q < 8; ++q) {
                int jj = (q < rem) ? (j + q) : j;
                s[q] = __shfl(cv, jj);
            }
#pragma unroll
            for (int q = 0; q < 8; ++q) as[q] = a_s[(size_t)s[q] * H + h];
#pragma unroll
            for (int q = 0; q < 8; ++q) uv[q] = *(const unsigned*)(xlj + (size_t)s[q] * 128);
#pragma unroll
            for (int q = 0; q < 8; ++q) {
                float al = as[q] + ad;
                al = (al >= 0.f) ? al : LEAKY_SLOPE * al;
                float w = (q < rem) ? __expf(al) : 0.f;
                accx = fmaf(w, bflo(uv[q]), accx);
                accy = fmaf(w, bfhi(uv[q]), accy);
                den += w;
            }
        }
    }

    float inv = 1.0f / (den + 1e-16f);
    int j = 2 * lane;
    float o0 = fmaxf(fmaf(accx, inv, bias[j]),     0.f);
    float o1 = fmaxf(fmaf(accy, inv, bias[j + 1]), 0.f);
    unsigned pk = (unsigned)f2bf(o0) | ((unsigned)f2bf(o1) << 16);
    *(unsigned*)(outb + (size_t)node * 128 + j) = pk;
}

// ---------------------------------------------------------------------------
extern "C" void kernel_launch(void* const* d_in, const int* in_sizes, int n_in,
                              void* d_out, int out_size, void* d_ws, size_t ws_size,
                              hipStream_t stream)
{
    const float* x   = (const float*)d_in[0];
    const int*   ei  = (const int*)d_in[1];
    const float* W0  = (const float*)d_in[2];
    const float* as0 = (const float*)d_in[3];
    const float* ad0 = (const float*)d_in[4];
    const float* b0  = (const float*)d_in[5];
    const float* W1  = (const float*)d_in[6];
    const float* as1 = (const float*)d_in[7];
    const float* ad1 = (const float*)d_in[8];
    const float* b1  = (const float*)d_in[9];
    const float* Wn  = (const float*)d_in[10];
    const float* bn  = (const float*)d_in[11];
    const float* We  = (const float*)d_in[12];
    const float* be  = (const float*)d_in[13];

    const int n  = in_sizes[0] / 128;
    const int E  = in_sizes[1] / 2;
    const int ET = E + n;
    float* out = (float*)d_out;

    char* w = (char*)d_ws;
    auto carve = [&](size_t bytes) -> void* {
        void* p = (void*)w;
        w += (bytes + 255) & ~(size_t)255;
        return p;
    };
    unsigned short* xb  = (unsigned short*)carve((size_t)n * 128 * 2);
    unsigned short* xlb = (unsigned short*)carve((size_t)n * 128 * 2);
    unsigned short* hb  = (unsigned short*)carve((size_t)n * 128 * 2);
    float* a_s  = (float*)carve((size_t)n * 4 * 4);
    float* a_d  = (float*)carve((size_t)n * 4 * 4);
    int*   curs = (int*)carve((size_t)n * 16 * 4);     // padded: 1 counter / 64B
    int*   rowp = (int*)carve((size_t)(n + 1) * 4);
    int*   slot = (int*)carve((size_t)ET * 4);
    int*   colv = (int*)carve((size_t)ET * 4);
    int*   bsum = (int*)carve(1024);
    int*   boff = (int*)carve(1024);
    unsigned short* P0 = (unsigned short*)carve(16384 * 2);
    unsigned short* P1 = (unsigned short*)carve(16384 * 2);
    unsigned short* Pn = (unsigned short*)carve(8192 * 2);
    unsigned short* Pe = (unsigned short*)carve(8192 * 2);

    const int gN64 = (n + 63) / 64;
    const int gWv  = (n + 3) / 4;
    const int gE   = (ET + 255) / 256;
    const int NB   = (n + 255) / 256;

    // ---- prep: cast + pack + zero (fused) ----
    const int prepWork = n * 32 + 49152 + n * 16;
    prep_k<<<(prepWork + 255) / 256, 256, 0, stream>>>(x, W0, W1, Wn, We,
                                                       xb, P0, P1, Pn, Pe, curs, n);

    // ---- CSR by destination (shared by both layers) ----
    scat1_k<<<gE, 256, 0, stream>>>(ei, curs, slot, E, n);
    scanA_k<<<NB, 256, 0, stream>>>(curs, rowp, bsum, n);
    scanB_k<<<1, 256, 0, stream>>>(bsum, boff, NB);
    scanC_k<<<(n + 256) / 256, 256, 0, stream>>>(rowp, boff, n, ET);
    scat2_k<<<gE, 256, 0, stream>>>(ei, rowp, slot, colv, E, n);

    // ---- layer 0: H=4, C=32 (att fused into gemm epilogue) ----
    gemm_mfma_k<128, 4, false><<<gN64, 256, 0, stream>>>(xb, P0, nullptr, xlb, nullptr,
                                                         as0, ad0, a_s, a_d, n);
    agg_k<4><<<gWv, 256, 0, stream>>>(xlb, a_s, a_d, rowp, colv, b0, hb, n);

    // ---- layer 1: H=1, C=128 ----
    gemm_mfma_k<128, 1, false><<<gN64, 256, 0, stream>>>(hb, P1, nullptr, xlb, nullptr,
                                                         as1, ad1, a_s, a_d, n);
    agg_k<1><<<gWv, 256, 0, stream>>>(xlb, a_s, a_d, rowp, colv, b1, hb, n);

    // ---- projection heads: out = [h_ego || h_neighbor] ----
    gemm_mfma_k<64, 0, true><<<gN64, 256, 0, stream>>>(xb, Pe, be, nullptr, out,
                                                       nullptr, nullptr, nullptr, nullptr, n);
    gemm_mfma_k<64, 0, true><<<gN64, 256, 0, stream>>>(hb, Pn, bn, nullptr, out + (size_t)n * 64,
                                                       nullptr, nullptr, nullptr, nullptr, n);
}

// Round 6
// 275.537 us; speedup vs baseline: 1.7859x; 1.0113x over previous
//
#include <hip/hip_runtime.h>

// ---------------------------------------------------------------------------
// GAT GNN: h0 = relu(GAT0(x)); h1 = relu(GAT1(h0));
// out = [x@We+be  ||  h1@Wn+bn]
// R3: bf16 features + MFMA GEMMs.  R4: low-contention 2-phase CSR build.
// R5: att logits fused into GEMM epilogue; prep fused.
// R6: agg_k split-lane (32 lanes/edge, dwordx2 gathers, 16 edges/batch in
//     flight); scanC folded into scat2; projection GEMMs merged (grid.y=2).
// ---------------------------------------------------------------------------

#define LEAKY_SLOPE 0.2f

typedef __attribute__((ext_vector_type(8))) short s16x8;
typedef __attribute__((ext_vector_type(4))) float f32x4;

static __device__ __forceinline__ unsigned short f2bf(float f)
{
    unsigned x = __float_as_uint(f);
    unsigned r = (x + 0x7fffu + ((x >> 16) & 1u)) >> 16;   // RNE
    return (unsigned short)r;
}
static __device__ __forceinline__ float bfhi(unsigned u) { return __uint_as_float(u & 0xffff0000u); }
static __device__ __forceinline__ float bflo(unsigned u) { return __uint_as_float(u << 16); }

// ---------------- prep: cast x->bf16, pack 4 weight mats, zero cursors -----
__global__ __launch_bounds__(256) void prep_k(const float* __restrict__ x,
                                              const float* __restrict__ W0,
                                              const float* __restrict__ W1,
                                              const float* __restrict__ Wn,
                                              const float* __restrict__ We,
                                              unsigned short* __restrict__ xb,
                                              unsigned short* __restrict__ P0,
                                              unsigned short* __restrict__ P1,
                                              unsigned short* __restrict__ Pn,
                                              unsigned short* __restrict__ Pe,
                                              int* __restrict__ curs, int n)
{
    int gid = blockIdx.x * 256 + threadIdx.x;
    int nc = n * 32;                       // float4 count of x
    if (gid < nc) {
        float4 v = ((const float4*)x)[gid];
        ushort4 o;
        o.x = f2bf(v.x); o.y = f2bf(v.y); o.z = f2bf(v.z); o.w = f2bf(v.w);
        ((ushort4*)xb)[gid] = o;
    } else if (gid < nc + 49152) {
        int idx = gid - nc;
        const float* S; unsigned short* D; int BN; int local;
        if (idx < 16384)      { S = W0; D = P0; BN = 128; local = idx; }
        else if (idx < 32768) { S = W1; D = P1; BN = 128; local = idx - 16384; }
        else if (idx < 40960) { S = Wn; D = Pn; BN = 64;  local = idx - 32768; }
        else                  { S = We; D = Pe; BN = 64;  local = idx - 40960; }
        int k = local / BN, nn = local % BN;
        D[(((k >> 3) * BN + nn) * 8) + (k & 7)] = f2bf(S[local]);
    } else if (gid < nc + 49152 + n * 16) {
        curs[gid - nc - 49152] = 0;
    }
}

// ---------------- MFMA GEMM (BN=128) + fused attention logits --------------
// HATT=4: layer0 logits (per-head in-wave). HATT=1: layer1 (LDS combine).
template<int HATT>
__global__ __launch_bounds__(256) void gemm_mfma_k(const unsigned short* __restrict__ Ab,
                                                   const unsigned short* __restrict__ Bp,
                                                   unsigned short* __restrict__ Cb,
                                                   const float* __restrict__ ats,
                                                   const float* __restrict__ atd,
                                                   float* __restrict__ a_s,
                                                   float* __restrict__ a_d, int n)
{
    constexpr int BN = 128;
    constexpr int APITCH = 144;
    constexpr int BPITCH = BN + 2;

    __shared__ unsigned short As[64 * APITCH];
    __shared__ unsigned short Bs[16 * BPITCH * 8];
    __shared__ float smS[64][2], smD[64][2];       // HATT==1 combine (1 KB)

    const int t  = threadIdx.x;
    const int rb = blockIdx.x * 64;

#pragma unroll
    for (int i = 0; i < 4; ++i) {
        int q = t + i * 256;
        int r = q >> 4;
        int c = (q & 15) * 8;
        float4 v = make_float4(0.f, 0.f, 0.f, 0.f);
        int gr = rb + r;
        if (gr < n) v = *(const float4*)(Ab + (size_t)gr * 128 + c);
        *(float4*)(As + r * APITCH + c) = v;
    }
#pragma unroll
    for (int i = 0; i < 8; ++i) {
        int ge = t + i * 256;
        int o = ge / BN, nn = ge % BN;
        *(float4*)(Bs + ((size_t)o * BPITCH + nn) * 8) = *(const float4*)(Bp + (size_t)ge * 8);
    }
    __syncthreads();

    const int w = t >> 6, lane = t & 63;
    const int m = lane & 15, quad = lane >> 4;
    const int wc = w & 1, wr = w >> 1;
    const int row0 = wr * 32;
    const int col0 = wc * 64;

    f32x4 acc[2][4];
#pragma unroll
    for (int rt = 0; rt < 2; ++rt)
#pragma unroll
        for (int c = 0; c < 4; ++c) acc[rt][c] = (f32x4){0.f, 0.f, 0.f, 0.f};

    s16x8 a[2][4];
#pragma unroll
    for (int rt = 0; rt < 2; ++rt)
#pragma unroll
        for (int kk = 0; kk < 4; ++kk)
            a[rt][kk] = *(const s16x8*)(As + (row0 + rt * 16 + m) * APITCH + kk * 32 + quad * 8);

#pragma unroll
    for (int kk = 0; kk < 4; ++kk)
#pragma unroll
        for (int c = 0; c < 4; ++c) {
            s16x8 b = *(const s16x8*)(Bs + ((size_t)(kk * 4 + quad) * BPITCH + col0 + c * 16 + m) * 8);
#pragma unroll
            for (int rt = 0; rt < 2; ++rt)
                acc[rt][c] = __builtin_amdgcn_mfma_f32_16x16x32_bf16(a[rt][kk], b, acc[rt][c], 0, 0, 0);
        }

    // ---- C store (C/D layout: col=lane&15, row=quad*4+reg) ----
#pragma unroll
    for (int rt = 0; rt < 2; ++rt)
#pragma unroll
        for (int c = 0; c < 4; ++c)
#pragma unroll
            for (int r = 0; r < 4; ++r) {
                int row = rb + row0 + rt * 16 + quad * 4 + r;
                int colg = col0 + c * 16 + m;
                if (row < n) Cb[(size_t)row * 128 + colg] = f2bf(acc[rt][c][r]);
            }

    // ---- fused attention logits ----
    float atsv[4], atdv[4];
#pragma unroll
    for (int c = 0; c < 4; ++c) {
        atsv[c] = ats[col0 + c * 16 + m];
        atdv[c] = atd[col0 + c * 16 + m];
    }
    if (HATT == 4) {
#pragma unroll
        for (int rt = 0; rt < 2; ++rt)
#pragma unroll
            for (int r = 0; r < 4; ++r)
#pragma unroll
                for (int hb = 0; hb < 2; ++hb) {
                    float ps = acc[rt][2*hb][r] * atsv[2*hb] + acc[rt][2*hb+1][r] * atsv[2*hb+1];
                    float pd = acc[rt][2*hb][r] * atdv[2*hb] + acc[rt][2*hb+1][r] * atdv[2*hb+1];
#pragma unroll
                    for (int off = 1; off < 16; off <<= 1) {
                        ps += __shfl_xor(ps, off);
                        pd += __shfl_xor(pd, off);
                    }
                    int row = rb + row0 + rt * 16 + quad * 4 + r;
                    if (m == 0 && row < n) {
                        a_s[(size_t)row * 4 + 2*wc + hb] = ps;
                        a_d[(size_t)row * 4 + 2*wc + hb] = pd;
                    }
                }
    }
    if (HATT == 1) {
#pragma unroll
        for (int rt = 0; rt < 2; ++rt)
#pragma unroll
            for (int r = 0; r < 4; ++r) {
                float ps = 0.f, pd = 0.f;
#pragma unroll
                for (int c = 0; c < 4; ++c) {
                    ps = fmaf(acc[rt][c][r], atsv[c], ps);
                    pd = fmaf(acc[rt][c][r], atdv[c], pd);
                }
#pragma unroll
                for (int off = 1; off < 16; off <<= 1) {
                    ps += __shfl_xor(ps, off);
                    pd += __shfl_xor(pd, off);
                }
                int lrow = row0 + rt * 16 + quad * 4 + r;
                if (m == 0) { smS[lrow][wc] = ps; smD[lrow][wc] = pd; }
            }
        __syncthreads();
        if (t < 64) {
            int row = rb + t;
            if (row < n) {
                a_s[row] = smS[t][0] + smS[t][1];
                a_d[row] = smD[t][0] + smD[t][1];
            }
        }
    }
}

// ---------------- projection heads: one dispatch, grid.y selects pair ------
__global__ __launch_bounds__(256) void gemm_proj_k(const unsigned short* __restrict__ A0,
                                                   const unsigned short* __restrict__ A1,
                                                   const unsigned short* __restrict__ B0,
                                                   const unsigned short* __restrict__ B1,
                                                   const float* __restrict__ bias0,
                                                   const float* __restrict__ bias1,
                                                   float* __restrict__ out, int n)
{
    constexpr int BN = 64;
    constexpr int APITCH = 144;
    constexpr int BPITCH = BN + 2;

    const unsigned short* Ab = blockIdx.y ? A1 : A0;
    const unsigned short* Bp = blockIdx.y ? B1 : B0;
    const float* bias        = blockIdx.y ? bias1 : bias0;
    float* Cf = out + (blockIdx.y ? (size_t)n * 64 : 0);

    __shared__ unsigned short As[64 * APITCH];
    __shared__ unsigned short Bs[16 * BPITCH * 8];

    const int t  = threadIdx.x;
    const int rb = blockIdx.x * 64;

#pragma unroll
    for (int i = 0; i < 4; ++i) {
        int q = t + i * 256;
        int r = q >> 4;
        int c = (q & 15) * 8;
        float4 v = make_float4(0.f, 0.f, 0.f, 0.f);
        int gr = rb + r;
        if (gr < n) v = *(const float4*)(Ab + (size_t)gr * 128 + c);
        *(float4*)(As + r * APITCH + c) = v;
    }
#pragma unroll
    for (int i = 0; i < 4; ++i) {
        int ge = t + i * 256;
        int o = ge / BN, nn = ge % BN;
        *(float4*)(Bs + ((size_t)o * BPITCH + nn) * 8) = *(const float4*)(Bp + (size_t)ge * 8);
    }
    __syncthreads();

    const int w = t >> 6, lane = t & 63;
    const int m = lane & 15, quad = lane >> 4;
    const int row0 = w * 16;

    f32x4 acc[4];
#pragma unroll
    for (int c = 0; c < 4; ++c) acc[c] = (f32x4){0.f, 0.f, 0.f, 0.f};

    s16x8 a[4];
#pragma unroll
    for (int kk = 0; kk < 4; ++kk)
        a[kk] = *(const s16x8*)(As + (row0 + m) * APITCH + kk * 32 + quad * 8);

#pragma unroll
    for (int kk = 0; kk < 4; ++kk)
#pragma unroll
        for (int c = 0; c < 4; ++c) {
            s16x8 b = *(const s16x8*)(Bs + ((size_t)(kk * 4 + quad) * BPITCH + c * 16 + m) * 8);
            acc[c] = __builtin_amdgcn_mfma_f32_16x16x32_bf16(a[kk], b, acc[c], 0, 0, 0);
        }

#pragma unroll
    for (int c = 0; c < 4; ++c)
#pragma unroll
        for (int r = 0; r < 4; ++r) {
            int row = rb + row0 + quad * 4 + r;
            int colg = c * 16 + m;
            if (row < n) Cf[(size_t)row * BN + colg] = acc[c][r] + bias[colg];
        }
}

// ---------------- CSR build ------------------------------------------------
// Phase 1: fused count + slot assignment; cursP padded 1 counter / 64B line.
__global__ void scat1_k(const int* __restrict__ ei, int* __restrict__ cursP,
                        int* __restrict__ slot, int E, int n)
{
    int e = blockIdx.x * 256 + threadIdx.x;
    if (e >= E + n) return;
    int d = (e < E) ? ei[E + e] : (e - E);   // self-loop dst = node id
    slot[e] = atomicAdd(&cursP[d << 4], 1);
}

__global__ void scanA_k(const int* __restrict__ cursP, int* __restrict__ excl,
                        int* __restrict__ bsum, int n)
{
    __shared__ int sm[256];
    int t = threadIdx.x, i = blockIdx.x * 256 + t;
    int v = (i < n) ? cursP[i << 4] : 0;
    sm[t] = v;
    __syncthreads();
    for (int off = 1; off < 256; off <<= 1) {
        int x = (t >= off) ? sm[t - off] : 0;
        __syncthreads();
        sm[t] += x;
        __syncthreads();
    }
    if (i < n) excl[i] = sm[t] - v;
    if (t == 255) bsum[blockIdx.x] = sm[t];
}

__global__ void scanB_k(const int* __restrict__ bsum, int* __restrict__ boff, int nb)
{
    __shared__ int sm[256];
    int t = threadIdx.x;
    int v = (t < nb) ? bsum[t] : 0;
    sm[t] = v;
    __syncthreads();
    for (int off = 1; off < 256; off <<= 1) {
        int x = (t >= off) ? sm[t - off] : 0;
        __syncthreads();
        sm[t] += x;
        __syncthreads();
    }
    if (t < nb) boff[t] = sm[t] - v;
}

// Phase 2 (R6: scanC folded in): scatter with on-the-fly rowptr finalization;
// final rowptr written to rowf (separate array -> no read/write race).
__global__ void scat2_k(const int* __restrict__ ei, const int* __restrict__ rowe,
                        const int* __restrict__ boff, const int* __restrict__ slot,
                        int* __restrict__ col, int* __restrict__ rowf,
                        int E, int n)
{
    int e = blockIdx.x * 256 + threadIdx.x;
    int ET = E + n;
    if (e < ET) {
        int s = (e < E) ? ei[e]     : (e - E);
        int d = (e < E) ? ei[E + e] : (e - E);
        int base = rowe[d] + boff[d >> 8];
        col[base + slot[e]] = s;
    }
    if (e <= n) rowf[e] = (e < n) ? (rowe[e] + boff[e >> 8]) : ET;
}

// ---------------- GAT aggregation (R6 split-lane) --------------------------
// One wave per dst node; 32 lanes per edge (4 ch/lane, dwordx2 gather);
// sub-wave 0 handles edges j..j+7, sub-wave 1 j+8..j+15 -> 16 edges in
// flight per batch. Cross-sub combine via shfl_xor(32).
template<int H>
__global__ __launch_bounds__(256) void agg_k(const unsigned short* __restrict__ xlb,
                                             const float* __restrict__ a_s,
                                             const float* __restrict__ a_d,
                                             const int* __restrict__ rowptr,
                                             const int* __restrict__ col,
                                             const float* __restrict__ bias,
                                             unsigned short* __restrict__ outb, int n)
{
    int node = (blockIdx.x * 256 + threadIdx.x) >> 6;
    int lane = threadIdx.x & 63;
    if (node >= n) return;
    const int sub = lane >> 5, sl = lane & 31;
    const int h = (H == 1) ? 0 : (sl >> 3);          // 4 ch/lane, C=32 per head
    float ad = a_d[(size_t)node * H + h];
    int p0 = rowptr[node], p1 = rowptr[node + 1];
    float a0 = 0.f, a1 = 0.f, a2 = 0.f, a3 = 0.f, den = 0.f;
    const unsigned short* xlj = xlb + 4 * sl;

    for (int base = p0; base < p1; base += 64) {
        int m = p1 - base;
        if (m > 64) m = 64;
        int cv = col[base + (lane < m ? lane : m - 1)];
        int j = 0;
        for (; j + 16 <= m; j += 16) {
            int jb = j + 8 * sub;
            int s[8]; float as[8]; uint2 uv[8];
#pragma unroll
            for (int q = 0; q < 8; ++q) s[q] = __shfl(cv, jb + q);
#pragma unroll
            for (int q = 0; q < 8; ++q) as[q] = a_s[(size_t)s[q] * H + h];
#pragma unroll
            for (int q = 0; q < 8; ++q) uv[q] = *(const uint2*)(xlj + (size_t)s[q] * 128);
#pragma unroll
            for (int q = 0; q < 8; ++q) {
                float al = as[q] + ad;
                al = (al >= 0.f) ? al : LEAKY_SLOPE * al;
                float w = __expf(al);
                a0 = fmaf(w, bflo(uv[q].x), a0);
                a1 = fmaf(w, bfhi(uv[q].x), a1);
                a2 = fmaf(w, bflo(uv[q].y), a2);
                a3 = fmaf(w, bfhi(uv[q].y), a3);
                den += w;
            }
        }
        int rem = m - j;
        if (rem > 0) {
            int cnt = sub ? (rem > 8 ? rem - 8 : 0) : (rem < 8 ? rem : 8);
            int jb = j + 8 * sub;
            int s[8]; float as[8]; uint2 uv[8];
#pragma unroll
            for (int q = 0; q < 8; ++q) s[q] = __shfl(cv, (q < cnt) ? (jb + q) : j);
#pragma unroll
            for (int q = 0; q < 8; ++q) as[q] = a_s[(size_t)s[q] * H + h];
#pragma unroll
            for (int q = 0; q < 8; ++q) uv[q] = *(const uint2*)(xlj + (size_t)s[q] * 128);
#pragma unroll
            for (int q = 0; q < 8; ++q) {
                float al = as[q] + ad;
                al = (al >= 0.f) ? al : LEAKY_SLOPE * al;
                float w = (q < cnt) ? __expf(al) : 0.f;
                a0 = fmaf(w, bflo(uv[q].x), a0);
                a1 = fmaf(w, bfhi(uv[q].x), a1);
                a2 = fmaf(w, bflo(uv[q].y), a2);
                a3 = fmaf(w, bfhi(uv[q].y), a3);
                den += w;
            }
        }
    }

    // combine sub-waves
    a0 += __shfl_xor(a0, 32);
    a1 += __shfl_xor(a1, 32);
    a2 += __shfl_xor(a2, 32);
    a3 += __shfl_xor(a3, 32);
    den += __shfl_xor(den, 32);

    if (sub == 0) {
        float inv = 1.0f / (den + 1e-16f);
        int j = 4 * sl;
        float o0 = fmaxf(fmaf(a0, inv, bias[j]),     0.f);
        float o1 = fmaxf(fmaf(a1, inv, bias[j + 1]), 0.f);
        float o2 = fmaxf(fmaf(a2, inv, bias[j + 2]), 0.f);
        float o3 = fmaxf(fmaf(a3, inv, bias[j + 3]), 0.f);
        uint2 pk;
        pk.x = (unsigned)f2bf(o0) | ((unsigned)f2bf(o1) << 16);
        pk.y = (unsigned)f2bf(o2) | ((unsigned)f2bf(o3) << 16);
        *(uint2*)(outb + (size_t)node * 128 + j) = pk;
    }
}

// ---------------------------------------------------------------------------
extern "C" void kernel_launch(void* const* d_in, const int* in_sizes, int n_in,
                              void* d_out, int out_size, void* d_ws, size_t ws_size,
                              hipStream_t stream)
{
    const float* x   = (const float*)d_in[0];
    const int*   ei  = (const int*)d_in[1];
    const float* W0  = (const float*)d_in[2];
    const float* as0 = (const float*)d_in[3];
    const float* ad0 = (const float*)d_in[4];
    const float* b0  = (const float*)d_in[5];
    const float* W1  = (const float*)d_in[6];
    const float* as1 = (const float*)d_in[7];
    const float* ad1 = (const float*)d_in[8];
    const float* b1  = (const float*)d_in[9];
    const float* Wn  = (const float*)d_in[10];
    const float* bn  = (const float*)d_in[11];
    const float* We  = (const float*)d_in[12];
    const float* be  = (const float*)d_in[13];

    const int n  = in_sizes[0] / 128;
    const int E  = in_sizes[1] / 2;
    const int ET = E + n;
    float* out = (float*)d_out;

    char* w = (char*)d_ws;
    auto carve = [&](size_t bytes) -> void* {
        void* p = (void*)w;
        w += (bytes + 255) & ~(size_t)255;
        return p;
    };
    unsigned short* xb  = (unsigned short*)carve((size_t)n * 128 * 2);
    unsigned short* xlb = (unsigned short*)carve((size_t)n * 128 * 2);
    unsigned short* hb  = (unsigned short*)carve((size_t)n * 128 * 2);
    float* a_s  = (float*)carve((size_t)n * 4 * 4);
    float* a_d  = (float*)carve((size_t)n * 4 * 4);
    int*   curs = (int*)carve((size_t)n * 16 * 4);     // padded: 1 counter / 64B
    int*   rowe = (int*)carve((size_t)n * 4);          // block-local excl scan
    int*   rowf = (int*)carve((size_t)(n + 1) * 4);    // final rowptr
    int*   slot = (int*)carve((size_t)ET * 4);
    int*   colv = (int*)carve((size_t)ET * 4);
    int*   bsum = (int*)carve(1024);
    int*   boff = (int*)carve(1024);
    unsigned short* P0 = (unsigned short*)carve(16384 * 2);
    unsigned short* P1 = (unsigned short*)carve(16384 * 2);
    unsigned short* Pn = (unsigned short*)carve(8192 * 2);
    unsigned short* Pe = (unsigned short*)carve(8192 * 2);

    const int gN64 = (n + 63) / 64;
    const int gWv  = (n + 3) / 4;
    const int gE   = (ET + 255) / 256;
    const int NB   = (n + 255) / 256;

    // ---- prep: cast + pack + zero (fused) ----
    const int prepWork = n * 32 + 49152 + n * 16;
    prep_k<<<(prepWork + 255) / 256, 256, 0, stream>>>(x, W0, W1, Wn, We,
                                                       xb, P0, P1, Pn, Pe, curs, n);

    // ---- CSR by destination (shared by both layers) ----
    scat1_k<<<gE, 256, 0, stream>>>(ei, curs, slot, E, n);
    scanA_k<<<NB, 256, 0, stream>>>(curs, rowe, bsum, n);
    scanB_k<<<1, 256, 0, stream>>>(bsum, boff, NB);
    scat2_k<<<gE, 256, 0, stream>>>(ei, rowe, boff, slot, colv, rowf, E, n);

    // ---- layer 0: H=4, C=32 (att fused into gemm epilogue) ----
    gemm_mfma_k<4><<<gN64, 256, 0, stream>>>(xb, P0, xlb, as0, ad0, a_s, a_d, n);
    agg_k<4><<<gWv, 256, 0, stream>>>(xlb, a_s, a_d, rowf, colv, b0, hb, n);

    // ---- layer 1: H=1, C=128 ----
    gemm_mfma_k<1><<<gN64, 256, 0, stream>>>(hb, P1, xlb, as1, ad1, a_s, a_d, n);
    agg_k<1><<<gWv, 256, 0, stream>>>(xlb, a_s, a_d, rowf, colv, b1, hb, n);

    // ---- projection heads: out = [x@We+be || h1@Wn+bn], one dispatch ----
    gemm_proj_k<<<dim3(gN64, 2), 256, 0, stream>>>(xb, hb, Pe, Pn, be, bn, out, n);
}

// Round 7
// 269.051 us; speedup vs baseline: 1.8290x; 1.0241x over previous
//
#include <hip/hip_runtime.h>

// ---------------------------------------------------------------------------
// GAT GNN: h0 = relu(GAT0(x)); h1 = relu(GAT1(h0));
// out = [x@We+be  ||  h1@Wn+bn]
// R3: bf16 features + MFMA GEMMs.  R4: low-contention 2-phase CSR build.
// R5: att logits fused into GEMM epilogue; prep fused.  R6: split-lane agg.
// R7: concurrency via grid-partitioned dispatches —
//     D2 = [gemm0 || scat1], D4 = [proj_ego || scat2];
//     scanA+scanB merged via device-scope completion counter.
//     10 -> 8 dispatches; gemm0/proj_e hidden under CSR-build work.
// ---------------------------------------------------------------------------

#define LEAKY_SLOPE 0.2f

typedef __attribute__((ext_vector_type(8))) short s16x8;
typedef __attribute__((ext_vector_type(4))) float f32x4;

static __device__ __forceinline__ unsigned short f2bf(float f)
{
    unsigned x = __float_as_uint(f);
    unsigned r = (x + 0x7fffu + ((x >> 16) & 1u)) >> 16;   // RNE
    return (unsigned short)r;
}
static __device__ __forceinline__ float bfhi(unsigned u) { return __uint_as_float(u & 0xffff0000u); }
static __device__ __forceinline__ float bflo(unsigned u) { return __uint_as_float(u << 16); }

// ---------------- prep: cast x->bf16, pack 4 weight mats, zero cursors -----
__global__ __launch_bounds__(256) void prep_k(const float* __restrict__ x,
                                              const float* __restrict__ W0,
                                              const float* __restrict__ W1,
                                              const float* __restrict__ Wn,
                                              const float* __restrict__ We,
                                              unsigned short* __restrict__ xb,
                                              unsigned short* __restrict__ P0,
                                              unsigned short* __restrict__ P1,
                                              unsigned short* __restrict__ Pn,
                                              unsigned short* __restrict__ Pe,
                                              int* __restrict__ curs, int n)
{
    int gid = blockIdx.x * 256 + threadIdx.x;
    int nc = n * 32;                       // float4 count of x
    if (gid < nc) {
        float4 v = ((const float4*)x)[gid];
        ushort4 o;
        o.x = f2bf(v.x); o.y = f2bf(v.y); o.z = f2bf(v.z); o.w = f2bf(v.w);
        ((ushort4*)xb)[gid] = o;
    } else if (gid < nc + 49152) {
        int idx = gid - nc;
        const float* S; unsigned short* D; int BN; int local;
        if (idx < 16384)      { S = W0; D = P0; BN = 128; local = idx; }
        else if (idx < 32768) { S = W1; D = P1; BN = 128; local = idx - 16384; }
        else if (idx < 40960) { S = Wn; D = Pn; BN = 64;  local = idx - 32768; }
        else                  { S = We; D = Pe; BN = 64;  local = idx - 40960; }
        int k = local / BN, nn = local % BN;
        D[(((k >> 3) * BN + nn) * 8) + (k & 7)] = f2bf(S[local]);
    } else if (gid < nc + 49152 + n * 16 + 16) {
        curs[gid - nc - 49152] = 0;        // cursors + done counter
    }
}

// ---------------- MFMA GEMM body (BN=128) + fused attention logits ---------
// HATT=4: layer0 logits (per-head in-wave). HATT=1: layer1 (LDS combine).
template<int HATT>
static __device__ __forceinline__ void gemm128_body(int tile,
                                                    const unsigned short* __restrict__ Ab,
                                                    const unsigned short* __restrict__ Bp,
                                                    unsigned short* __restrict__ Cb,
                                                    const float* __restrict__ ats,
                                                    const float* __restrict__ atd,
                                                    float* __restrict__ a_s,
                                                    float* __restrict__ a_d, int n)
{
    constexpr int BN = 128;
    constexpr int APITCH = 144;
    constexpr int BPITCH = BN + 2;

    __shared__ unsigned short As[64 * APITCH];
    __shared__ unsigned short Bs[16 * BPITCH * 8];
    __shared__ float smS[64][2], smD[64][2];       // HATT==1 combine (1 KB)

    const int t  = threadIdx.x;
    const int rb = tile * 64;

#pragma unroll
    for (int i = 0; i < 4; ++i) {
        int q = t + i * 256;
        int r = q >> 4;
        int c = (q & 15) * 8;
        float4 v = make_float4(0.f, 0.f, 0.f, 0.f);
        int gr = rb + r;
        if (gr < n) v = *(const float4*)(Ab + (size_t)gr * 128 + c);
        *(float4*)(As + r * APITCH + c) = v;
    }
#pragma unroll
    for (int i = 0; i < 8; ++i) {
        int ge = t + i * 256;
        int o = ge / BN, nn = ge % BN;
        *(float4*)(Bs + ((size_t)o * BPITCH + nn) * 8) = *(const float4*)(Bp + (size_t)ge * 8);
    }
    __syncthreads();

    const int w = t >> 6, lane = t & 63;
    const int m = lane & 15, quad = lane >> 4;
    const int wc = w & 1, wr = w >> 1;
    const int row0 = wr * 32;
    const int col0 = wc * 64;

    f32x4 acc[2][4];
#pragma unroll
    for (int rt = 0; rt < 2; ++rt)
#pragma unroll
        for (int c = 0; c < 4; ++c) acc[rt][c] = (f32x4){0.f, 0.f, 0.f, 0.f};

    s16x8 a[2][4];
#pragma unroll
    for (int rt = 0; rt < 2; ++rt)
#pragma unroll
        for (int kk = 0; kk < 4; ++kk)
            a[rt][kk] = *(const s16x8*)(As + (row0 + rt * 16 + m) * APITCH + kk * 32 + quad * 8);

#pragma unroll
    for (int kk = 0; kk < 4; ++kk)
#pragma unroll
        for (int c = 0; c < 4; ++c) {
            s16x8 b = *(const s16x8*)(Bs + ((size_t)(kk * 4 + quad) * BPITCH + col0 + c * 16 + m) * 8);
#pragma unroll
            for (int rt = 0; rt < 2; ++rt)
                acc[rt][c] = __builtin_amdgcn_mfma_f32_16x16x32_bf16(a[rt][kk], b, acc[rt][c], 0, 0, 0);
        }

    // ---- C store (C/D layout: col=lane&15, row=quad*4+reg) ----
#pragma unroll
    for (int rt = 0; rt < 2; ++rt)
#pragma unroll
        for (int c = 0; c < 4; ++c)
#pragma unroll
            for (int r = 0; r < 4; ++r) {
                int row = rb + row0 + rt * 16 + quad * 4 + r;
                int colg = col0 + c * 16 + m;
                if (row < n) Cb[(size_t)row * 128 + colg] = f2bf(acc[rt][c][r]);
            }

    // ---- fused attention logits ----
    float atsv[4], atdv[4];
#pragma unroll
    for (int c = 0; c < 4; ++c) {
        atsv[c] = ats[col0 + c * 16 + m];
        atdv[c] = atd[col0 + c * 16 + m];
    }
    if (HATT == 4) {
#pragma unroll
        for (int rt = 0; rt < 2; ++rt)
#pragma unroll
            for (int r = 0; r < 4; ++r)
#pragma unroll
                for (int hb = 0; hb < 2; ++hb) {
                    float ps = acc[rt][2*hb][r] * atsv[2*hb] + acc[rt][2*hb+1][r] * atsv[2*hb+1];
                    float pd = acc[rt][2*hb][r] * atdv[2*hb] + acc[rt][2*hb+1][r] * atdv[2*hb+1];
#pragma unroll
                    for (int off = 1; off < 16; off <<= 1) {
                        ps += __shfl_xor(ps, off);
                        pd += __shfl_xor(pd, off);
                    }
                    int row = rb + row0 + rt * 16 + quad * 4 + r;
                    if (m == 0 && row < n) {
                        a_s[(size_t)row * 4 + 2*wc + hb] = ps;
                        a_d[(size_t)row * 4 + 2*wc + hb] = pd;
                    }
                }
    }
    if (HATT == 1) {
#pragma unroll
        for (int rt = 0; rt < 2; ++rt)
#pragma unroll
            for (int r = 0; r < 4; ++r) {
                float ps = 0.f, pd = 0.f;
#pragma unroll
                for (int c = 0; c < 4; ++c) {
                    ps = fmaf(acc[rt][c][r], atsv[c], ps);
                    pd = fmaf(acc[rt][c][r], atdv[c], pd);
                }
#pragma unroll
                for (int off = 1; off < 16; off <<= 1) {
                    ps += __shfl_xor(ps, off);
                    pd += __shfl_xor(pd, off);
                }
                int lrow = row0 + rt * 16 + quad * 4 + r;
                if (m == 0) { smS[lrow][wc] = ps; smD[lrow][wc] = pd; }
            }
        __syncthreads();
        if (t < 64) {
            int row = rb + t;
            if (row < n) {
                a_s[row] = smS[t][0] + smS[t][1];
                a_d[row] = smD[t][0] + smD[t][1];
            }
        }
    }
}

// ---------------- projection GEMM body (BN=64, fp32 out + bias) ------------
static __device__ __forceinline__ void proj64_body(int tile,
                                                   const unsigned short* __restrict__ Ab,
                                                   const unsigned short* __restrict__ Bp,
                                                   const float* __restrict__ bias,
                                                   float* __restrict__ Cf, int n)
{
    constexpr int BN = 64;
    constexpr int APITCH = 144;
    constexpr int BPITCH = BN + 2;

    __shared__ unsigned short As[64 * APITCH];
    __shared__ unsigned short Bs[16 * BPITCH * 8];

    const int t  = threadIdx.x;
    const int rb = tile * 64;

#pragma unroll
    for (int i = 0; i < 4; ++i) {
        int q = t + i * 256;
        int r = q >> 4;
        int c = (q & 15) * 8;
        float4 v = make_float4(0.f, 0.f, 0.f, 0.f);
        int gr = rb + r;
        if (gr < n) v = *(const float4*)(Ab + (size_t)gr * 128 + c);
        *(float4*)(As + r * APITCH + c) = v;
    }
#pragma unroll
    for (int i = 0; i < 4; ++i) {
        int ge = t + i * 256;
        int o = ge / BN, nn = ge % BN;
        *(float4*)(Bs + ((size_t)o * BPITCH + nn) * 8) = *(const float4*)(Bp + (size_t)ge * 8);
    }
    __syncthreads();

    const int w = t >> 6, lane = t & 63;
    const int m = lane & 15, quad = lane >> 4;
    const int row0 = w * 16;

    f32x4 acc[4];
#pragma unroll
    for (int c = 0; c < 4; ++c) acc[c] = (f32x4){0.f, 0.f, 0.f, 0.f};

    s16x8 a[4];
#pragma unroll
    for (int kk = 0; kk < 4; ++kk)
        a[kk] = *(const s16x8*)(As + (row0 + m) * APITCH + kk * 32 + quad * 8);

#pragma unroll
    for (int kk = 0; kk < 4; ++kk)
#pragma unroll
        for (int c = 0; c < 4; ++c) {
            s16x8 b = *(const s16x8*)(Bs + ((size_t)(kk * 4 + quad) * BPITCH + c * 16 + m) * 8);
            acc[c] = __builtin_amdgcn_mfma_f32_16x16x32_bf16(a[kk], b, acc[c], 0, 0, 0);
        }

#pragma unroll
    for (int c = 0; c < 4; ++c)
#pragma unroll
        for (int r = 0; r < 4; ++r) {
            int row = rb + row0 + quad * 4 + r;
            int colg = c * 16 + m;
            if (row < n) Cf[(size_t)row * BN + colg] = acc[c][r] + bias[colg];
        }
}

// ---------------- D2: [gemm0+att0 || scat1] --------------------------------
__global__ __launch_bounds__(256) void gemm0_scat1_k(const unsigned short* __restrict__ Ab,
                                                     const unsigned short* __restrict__ Bp,
                                                     unsigned short* __restrict__ Cb,
                                                     const float* __restrict__ ats,
                                                     const float* __restrict__ atd,
                                                     float* __restrict__ a_s,
                                                     float* __restrict__ a_d, int n,
                                                     const int* __restrict__ ei,
                                                     int* __restrict__ cursP,
                                                     int* __restrict__ slot, int E,
                                                     int gemmBlocks)
{
    if ((int)blockIdx.x < gemmBlocks) {
        gemm128_body<4>(blockIdx.x, Ab, Bp, Cb, ats, atd, a_s, a_d, n);
    } else {
        int e = (blockIdx.x - gemmBlocks) * 256 + threadIdx.x;
        if (e < E + n) {
            int d = (e < E) ? ei[E + e] : (e - E);   // self-loop dst = node id
            slot[e] = atomicAdd(&cursP[d << 4], 1);
        }
    }
}

// ---------------- D3: two-level exclusive scan, one dispatch ---------------
// Per-block scan of padded cursors -> rowe + bsum; device fence; last block
// (via done counter) scans bsum -> boff.  nb <= 256 required (n <= 65536).
__global__ __launch_bounds__(256) void scanAB_k(const int* __restrict__ cursP,
                                                int* __restrict__ rowe,
                                                int* __restrict__ bsum,
                                                int* __restrict__ boff,
                                                int* __restrict__ done,
                                                int n, int nb)
{
    __shared__ int sm[256];
    __shared__ int flag;
    int t = threadIdx.x, i = blockIdx.x * 256 + t;
    int v = (i < n) ? cursP[i << 4] : 0;
    sm[t] = v;
    __syncthreads();
    for (int off = 1; off < 256; off <<= 1) {
        int x = (t >= off) ? sm[t - off] : 0;
        __syncthreads();
        sm[t] += x;
        __syncthreads();
    }
    if (i < n) rowe[i] = sm[t] - v;
    if (t == 255) {
        bsum[blockIdx.x] = sm[t];
        __threadfence();                 // publish bsum device-wide
    }
    __syncthreads();
    if (t == 0) {
        int old = atomicAdd(done, 1);
        flag = (old == nb - 1) ? 1 : 0;
    }
    __syncthreads();
    if (flag) {                          // last block: scan the block sums
        __threadfence();                 // acquire all blocks' bsum
        int v2 = (t < nb) ? bsum[t] : 0;
        sm[t] = v2;
        __syncthreads();
        for (int off = 1; off < 256; off <<= 1) {
            int x = (t >= off) ? sm[t - off] : 0;
            __syncthreads();
            sm[t] += x;
            __syncthreads();
        }
        if (t < nb) boff[t] = sm[t] - v2;
    }
}

// ---------------- D4: [proj_ego || scat2+rowptr finalize] ------------------
__global__ __launch_bounds__(256) void scat2_proj_k(const int* __restrict__ ei,
                                                    const int* __restrict__ rowe,
                                                    const int* __restrict__ boff,
                                                    const int* __restrict__ slot,
                                                    int* __restrict__ col,
                                                    int* __restrict__ rowf,
                                                    int E, int n,
                                                    const unsigned short* __restrict__ Ab,
                                                    const unsigned short* __restrict__ Bp,
                                                    const float* __restrict__ bias,
                                                    float* __restrict__ Cf,
                                                    int projBlocks)
{
    if ((int)blockIdx.x < projBlocks) {
        proj64_body(blockIdx.x, Ab, Bp, bias, Cf, n);
    } else {
        int e = (blockIdx.x - projBlocks) * 256 + threadIdx.x;
        int ET = E + n;
        if (e < ET) {
            int s = (e < E) ? ei[e]     : (e - E);
            int d = (e < E) ? ei[E + e] : (e - E);
            int base = rowe[d] + boff[d >> 8];
            col[base + slot[e]] = s;
        }
        if (e <= n) rowf[e] = (e < n) ? (rowe[e] + boff[e >> 8]) : ET;
    }
}

// ---------------- standalone gemm1 / proj_n --------------------------------
__global__ __launch_bounds__(256) void gemm1_k(const unsigned short* __restrict__ Ab,
                                               const unsigned short* __restrict__ Bp,
                                               unsigned short* __restrict__ Cb,
                                               const float* __restrict__ ats,
                                               const float* __restrict__ atd,
                                               float* __restrict__ a_s,
                                               float* __restrict__ a_d, int n)
{
    gemm128_body<1>(blockIdx.x, Ab, Bp, Cb, ats, atd, a_s, a_d, n);
}

__global__ __launch_bounds__(256) void projN_k(const unsigned short* __restrict__ Ab,
                                               const unsigned short* __restrict__ Bp,
                                               const float* __restrict__ bias,
                                               float* __restrict__ Cf, int n)
{
    proj64_body(blockIdx.x, Ab, Bp, bias, Cf, n);
}

// ---------------- GAT aggregation (R6 split-lane) --------------------------
template<int H>
__global__ __launch_bounds__(256) void agg_k(const unsigned short* __restrict__ xlb,
                                             const float* __restrict__ a_s,
                                             const float* __restrict__ a_d,
                                             const int* __restrict__ rowptr,
                                             const int* __restrict__ col,
                                             const float* __restrict__ bias,
                                             unsigned short* __restrict__ outb, int n)
{
    int node = (blockIdx.x * 256 + threadIdx.x) >> 6;
    int lane = threadIdx.x & 63;
    if (node >= n) return;
    const int sub = lane >> 5, sl = lane & 31;
    const int h = (H == 1) ? 0 : (sl >> 3);          // 4 ch/lane, C=32 per head
    float ad = a_d[(size_t)node * H + h];
    int p0 = rowptr[node], p1 = rowptr[node + 1];
    float a0 = 0.f, a1 = 0.f, a2 = 0.f, a3 = 0.f, den = 0.f;
    const unsigned short* xlj = xlb + 4 * sl;

    for (int base = p0; base < p1; base += 64) {
        int m = p1 - base;
        if (m > 64) m = 64;
        int cv = col[base + (lane < m ? lane : m - 1)];
        int j = 0;
        for (; j + 16 <= m; j += 16) {
            int jb = j + 8 * sub;
            int s[8]; float as[8]; uint2 uv[8];
#pragma unroll
            for (int q = 0; q < 8; ++q) s[q] = __shfl(cv, jb + q);
#pragma unroll
            for (int q = 0; q < 8; ++q) as[q] = a_s[(size_t)s[q] * H + h];
#pragma unroll
            for (int q = 0; q < 8; ++q) uv[q] = *(const uint2*)(xlj + (size_t)s[q] * 128);
#pragma unroll
            for (int q = 0; q < 8; ++q) {
                float al = as[q] + ad;
                al = (al >= 0.f) ? al : LEAKY_SLOPE * al;
                float w = __expf(al);
                a0 = fmaf(w, bflo(uv[q].x), a0);
                a1 = fmaf(w, bfhi(uv[q].x), a1);
                a2 = fmaf(w, bflo(uv[q].y), a2);
                a3 = fmaf(w, bfhi(uv[q].y), a3);
                den += w;
            }
        }
        int rem = m - j;
        if (rem > 0) {
            int cnt = sub ? (rem > 8 ? rem - 8 : 0) : (rem < 8 ? rem : 8);
            int jb = j + 8 * sub;
            int s[8]; float as[8]; uint2 uv[8];
#pragma unroll
            for (int q = 0; q < 8; ++q) s[q] = __shfl(cv, (q < cnt) ? (jb + q) : j);
#pragma unroll
            for (int q = 0; q < 8; ++q) as[q] = a_s[(size_t)s[q] * H + h];
#pragma unroll
            for (int q = 0; q < 8; ++q) uv[q] = *(const uint2*)(xlj + (size_t)s[q] * 128);
#pragma unroll
            for (int q = 0; q < 8; ++q) {
                float al = as[q] + ad;
                al = (al >= 0.f) ? al : LEAKY_SLOPE * al;
                float w = (q < cnt) ? __expf(al) : 0.f;
                a0 = fmaf(w, bflo(uv[q].x), a0);
                a1 = fmaf(w, bfhi(uv[q].x), a1);
                a2 = fmaf(w, bflo(uv[q].y), a2);
                a3 = fmaf(w, bfhi(uv[q].y), a3);
                den += w;
            }
        }
    }

    // combine sub-waves
    a0 += __shfl_xor(a0, 32);
    a1 += __shfl_xor(a1, 32);
    a2 += __shfl_xor(a2, 32);
    a3 += __shfl_xor(a3, 32);
    den += __shfl_xor(den, 32);

    if (sub == 0) {
        float inv = 1.0f / (den + 1e-16f);
        int j = 4 * sl;
        float o0 = fmaxf(fmaf(a0, inv, bias[j]),     0.f);
        float o1 = fmaxf(fmaf(a1, inv, bias[j + 1]), 0.f);
        float o2 = fmaxf(fmaf(a2, inv, bias[j + 2]), 0.f);
        float o3 = fmaxf(fmaf(a3, inv, bias[j + 3]), 0.f);
        uint2 pk;
        pk.x = (unsigned)f2bf(o0) | ((unsigned)f2bf(o1) << 16);
        pk.y = (unsigned)f2bf(o2) | ((unsigned)f2bf(o3) << 16);
        *(uint2*)(outb + (size_t)node * 128 + j) = pk;
    }
}

// ---------------------------------------------------------------------------
extern "C" void kernel_launch(void* const* d_in, const int* in_sizes, int n_in,
                              void* d_out, int out_size, void* d_ws, size_t ws_size,
                              hipStream_t stream)
{
    const float* x   = (const float*)d_in[0];
    const int*   ei  = (const int*)d_in[1];
    const float* W0  = (const float*)d_in[2];
    const float* as0 = (const float*)d_in[3];
    const float* ad0 = (const float*)d_in[4];
    const float* b0  = (const float*)d_in[5];
    const float* W1  = (const float*)d_in[6];
    const float* as1 = (const float*)d_in[7];
    const float* ad1 = (const float*)d_in[8];
    const float* b1  = (const float*)d_in[9];
    const float* Wn  = (const float*)d_in[10];
    const float* bn  = (const float*)d_in[11];
    const float* We  = (const float*)d_in[12];
    const float* be  = (const float*)d_in[13];

    const int n  = in_sizes[0] / 128;
    const int E  = in_sizes[1] / 2;
    const int ET = E + n;
    float* out = (float*)d_out;

    char* w = (char*)d_ws;
    auto carve = [&](size_t bytes) -> void* {
        void* p = (void*)w;
        w += (bytes + 255) & ~(size_t)255;
        return p;
    };
    unsigned short* xb  = (unsigned short*)carve((size_t)n * 128 * 2);
    unsigned short* xlb = (unsigned short*)carve((size_t)n * 128 * 2);
    unsigned short* hb  = (unsigned short*)carve((size_t)n * 128 * 2);
    float* a_s  = (float*)carve((size_t)n * 4 * 4);
    float* a_d  = (float*)carve((size_t)n * 4 * 4);
    int*   curs = (int*)carve((size_t)(n * 16 + 16) * 4);  // padded cursors + done
    int*   rowe = (int*)carve((size_t)n * 4);              // block-local excl scan
    int*   rowf = (int*)carve((size_t)(n + 1) * 4);        // final rowptr
    int*   slot = (int*)carve((size_t)ET * 4);
    int*   colv = (int*)carve((size_t)ET * 4);
    int*   bsum = (int*)carve(1024);
    int*   boff = (int*)carve(1024);
    unsigned short* P0 = (unsigned short*)carve(16384 * 2);
    unsigned short* P1 = (unsigned short*)carve(16384 * 2);
    unsigned short* Pn = (unsigned short*)carve(8192 * 2);
    unsigned short* Pe = (unsigned short*)carve(8192 * 2);
    int* done = curs + (size_t)n * 16;

    const int gN64 = (n + 63) / 64;
    const int gWv  = (n + 3) / 4;
    const int gE   = (ET + 255) / 256;
    const int NB   = (n + 255) / 256;     // must be <= 256

    // ---- D1: prep (cast + pack + zero cursors/done) ----
    const int prepWork = n * 32 + 49152 + n * 16 + 16;
    prep_k<<<(prepWork + 255) / 256, 256, 0, stream>>>(x, W0, W1, Wn, We,
                                                       xb, P0, P1, Pn, Pe, curs, n);

    // ---- D2: [gemm0+att0 || scat1] ----
    gemm0_scat1_k<<<gN64 + gE, 256, 0, stream>>>(xb, P0, xlb, as0, ad0, a_s, a_d, n,
                                                 ei, curs, slot, E, gN64);

    // ---- D3: two-level scan (one dispatch) ----
    scanAB_k<<<NB, 256, 0, stream>>>(curs, rowe, bsum, boff, done, n, NB);

    // ---- D4: [proj_ego || scat2] ----
    scat2_proj_k<<<gN64 + gE, 256, 0, stream>>>(ei, rowe, boff, slot, colv, rowf, E, n,
                                                xb, Pe, be, out, gN64);

    // ---- D5: layer-0 aggregation ----
    agg_k<4><<<gWv, 256, 0, stream>>>(xlb, a_s, a_d, rowf, colv, b0, hb, n);

    // ---- D6: gemm1 + att1 ----
    gemm1_k<<<gN64, 256, 0, stream>>>(hb, P1, xlb, as1, ad1, a_s, a_d, n);

    // ---- D7: layer-1 aggregation ----
    agg_k<1><<<gWv, 256, 0, stream>>>(xlb, a_s, a_d, rowf, colv, b1, hb, n);

    // ---- D8: h_neighbor projection ----
    projN_k<<<gN64, 256, 0, stream>>>(hb, Pn, bn, out + (size_t)n * 64, n);
}